// Round 3
// baseline (1919.620 us; speedup 1.0000x reference)
//
#include <hip/hip_runtime.h>

// PACE DAG-transformer encoder, MI355X bf16-MFMA implementation. Round 3:
// LDS XOR-swizzle (kills 8-way read conflicts), double-buffered 2-phase
// prefetch in all GEMMs, residual+LayerNorm fused into O-proj/W2 GEMMs.

typedef unsigned short u16;
typedef unsigned int u32;
typedef __attribute__((ext_vector_type(8))) short bf16x8;
typedef __attribute__((ext_vector_type(4))) float f32x4;

#define NB 1024
#define MAXN 32
#define NHID 512
#define NHEAD 8
#define NLAY 6
#define MTOT (NB * MAXN)   // 32768 rows
#define ATT_SCALE 0.125f
#define LN_EPS 1e-5f

__device__ __forceinline__ float bf2f(u16 h) { return __uint_as_float(((u32)h) << 16); }
__device__ __forceinline__ u16 f2bf(float f) {
  u32 u = __float_as_uint(f);
  return (u16)((u + 0x7fffu + ((u >> 16) & 1u)) >> 16);
}

__device__ __forceinline__ void gload16(const void* g, void* l) {
  __builtin_amdgcn_global_load_lds((const __attribute__((address_space(1))) void*)g,
                                   (__attribute__((address_space(3))) void*)l, 16, 0, 0);
}

// ---------------------------------------------------------------------------
// DAG reachability mask: per (b,q) a 32-bit "allowed key" mask.
__global__ __launch_bounds__(256) void mask_k(const int* __restrict__ adj, u32* __restrict__ mask) {
  __shared__ u32 r[8][32];
  int tid = threadIdx.x;
  int g = tid >> 5, i = tid & 31;
  int b = blockIdx.x * 8 + g;
  const int* ab = adj + ((long)b * 32 + i) * 32;
  u32 m = 0;
  for (int j = i + 1; j < 32; ++j)
    if (ab[j]) m |= (1u << j);
  r[g][i] = m;
  __syncthreads();
  for (int it = 0; it < 5; ++it) {
    u32 cur = r[g][i];
    u32 acc = cur;
    #pragma unroll
    for (int j = 0; j < 32; ++j)
      if ((cur >> j) & 1u) acc |= r[g][j];
    __syncthreads();
    r[g][i] = acc;
    __syncthreads();
  }
  u32 am = 1u << i;
  #pragma unroll
  for (int k = 0; k < 32; ++k) am |= ((r[g][k] >> i) & 1u) << k;
  mask[b * 32 + i] = am;
}

// ---------------------------------------------------------------------------
// Embedding: x[:, :256] = relu(Wnode[type]+bnode); x[:, 256:] = Wpos[n]+bpos.
__global__ __launch_bounds__(256) void embed_k(const int* __restrict__ types,
    const float* __restrict__ Wpos, const float* __restrict__ bpos,
    const float* __restrict__ Wnode, const float* __restrict__ bnode,
    float* __restrict__ x, u16* __restrict__ xb) {
  int i = blockIdx.x * 256 + threadIdx.x;
  int row = i >> 7, c = (i & 127) * 4;
  int b = row >> 5, n = row & 31;
  float v[4];
  if (c < 256) {
    int tp = types[b * 32 + n];
    const float* w = &Wnode[tp * 256 + c];
    #pragma unroll
    for (int j = 0; j < 4; ++j) v[j] = fmaxf(w[j] + bnode[c + j], 0.f);
  } else {
    int cc = c - 256;
    const float* w = &Wpos[n * 256 + cc];
    #pragma unroll
    for (int j = 0; j < 4; ++j) v[j] = w[j] + bpos[cc + j];
  }
  long o = (long)row * NHID + c;
  *(float4*)&x[o] = make_float4(v[0], v[1], v[2], v[3]);
  ushort4 h; h.x = f2bf(v[0]); h.y = f2bf(v[1]); h.z = f2bf(v[2]); h.w = f2bf(v[3]);
  *(ushort4*)&xb[o] = h;
}

// ---------------------------------------------------------------------------
// Weight transpose + f32->bf16: W[l][k][n] -> Wt[l][n_off+n][k]
__global__ __launch_bounds__(256) void tconv_k(const float* __restrict__ W,
    u16* __restrict__ Wt, int n_off, int n_total) {
  __shared__ float tile[32][33];
  int l = blockIdx.z;
  int k0 = blockIdx.x * 32, n0 = blockIdx.y * 32;
  int tx = threadIdx.x & 31, ty = threadIdx.x >> 5;
  const float* src = W + (size_t)l * NHID * NHID;
  #pragma unroll
  for (int i = 0; i < 4; ++i)
    tile[ty + 8 * i][tx] = src[(size_t)(k0 + ty + 8 * i) * NHID + n0 + tx];
  __syncthreads();
  u16* dst = Wt + (size_t)l * n_total * NHID;
  #pragma unroll
  for (int i = 0; i < 4; ++i)
    dst[(size_t)(n_off + n0 + ty + 8 * i) * NHID + k0 + tx] = f2bf(tile[tx][ty + 8 * i]);
}

// ---------------------------------------------------------------------------
// bf16 MFMA GEMM: C[M][N] = A[M][K]*Bt[N][K]^T + bias. 128x128 tile, BK=32,
// double-buffered LDS with XOR-swizzled granules, 2-phase prefetch.
// EPI: 1 = bf16 out + bias; 2 = bf16 out + bias + relu
template <int EPI>
__global__ __launch_bounds__(256, 2) void gemm_bt(
    const u16* __restrict__ A, const u16* __restrict__ Bt,
    const float* __restrict__ bias0, const float* __restrict__ bias1,
    const float* __restrict__ bias2, u16* __restrict__ Cout, int N, int K) {
  __shared__ u16 AsB[2][128 * 32];
  __shared__ u16 BsB[2][128 * 32];
  const int tid = threadIdx.x;
  const int wave = tid >> 6, lane = tid & 63;
  const long m0 = (long)blockIdx.y * 128;
  const int n0 = blockIdx.x * 128;
  const int wr = wave >> 1, wc = wave & 1;
  const int srow = lane >> 2;                 // staged row within 16-row chunk
  const int sg = (lane & 3) ^ (srow & 3);     // pre-swizzled source granule
  const int fr = lane & 15;
  const int kq = lane >> 4;
  f32x4 acc[4][4] = {};

  auto stage = [&](int buf, int k0) {
    #pragma unroll
    for (int i = 0; i < 2; ++i) {
      int c = 2 * wave + i;
      gload16(A + (m0 + 16 * c + srow) * (long)K + k0 + sg * 8, &AsB[buf][c * 512]);
      gload16(Bt + (long)(n0 + 16 * c + srow) * K + k0 + sg * 8, &BsB[buf][c * 512]);
    }
  };
  stage(0, 0);
  __syncthreads();
  const int nt = K >> 5;
  const int kqx = (kq ^ (fr & 3)) * 8;        // swizzled read granule
  for (int t = 0; t < nt; ++t) {
    int cur = t & 1;
    if (t + 1 < nt) stage(cur ^ 1, (t + 1) * 32);
    const u16* As = AsB[cur];
    const u16* Bs = BsB[cur];
    bf16x8 af[4], bfv[4];
    #pragma unroll
    for (int mi = 0; mi < 4; ++mi)
      af[mi] = *(const bf16x8*)&As[(wr * 64 + mi * 16 + fr) * 32 + kqx];
    #pragma unroll
    for (int ni = 0; ni < 4; ++ni)
      bfv[ni] = *(const bf16x8*)&Bs[(wc * 64 + ni * 16 + fr) * 32 + kqx];
    #pragma unroll
    for (int mi = 0; mi < 4; ++mi)
      #pragma unroll
      for (int ni = 0; ni < 4; ++ni)
        acc[mi][ni] = __builtin_amdgcn_mfma_f32_16x16x32_bf16(af[mi], bfv[ni], acc[mi][ni], 0, 0, 0);
    __syncthreads();
  }

  #pragma unroll
  for (int ni = 0; ni < 4; ++ni) {
    int n = n0 + wc * 64 + ni * 16 + fr;
    const float* bp = (n < 512) ? bias0 : ((n < 1024) ? bias1 : bias2);
    float bias = bp[n & 511];
    #pragma unroll
    for (int mi = 0; mi < 4; ++mi) {
      long r = m0 + wr * 64 + mi * 16 + kq * 4;
      #pragma unroll
      for (int j = 0; j < 4; ++j) {
        float v = acc[mi][ni][j] + bias;
        if (EPI == 2) v = fmaxf(v, 0.f);
        Cout[(r + j) * (long)N + n] = f2bf(v);
      }
    }
  }
}

// ---------------------------------------------------------------------------
// GEMM + residual + LayerNorm fusion. Block tile 64x512 (full LN row),
// 4 waves of 64x128 (wave w = cols w*128..w*128+127). BK=32, dbuf+swizzle.
// x = LN(xf + A*Bt^T + bias) * g + b; writes xf (f32 master) and xb (bf16).
__global__ __launch_bounds__(256, 2) void gemm_ln(
    const u16* __restrict__ A, const u16* __restrict__ Bt,
    const float* __restrict__ bias, const float* __restrict__ g,
    const float* __restrict__ b, float* __restrict__ xf, u16* __restrict__ xb) {
  __shared__ u16 AsB[2][64 * 32];
  __shared__ u16 BsB[2][512 * 32];
  __shared__ float ps[4][64][2];
  const int tid = threadIdx.x;
  const int wave = tid >> 6, lane = tid & 63;
  const long m0 = (long)blockIdx.x * 64;
  const int srow = lane >> 2;
  const int sg = (lane & 3) ^ (srow & 3);
  const int fr = lane & 15;
  const int kq = lane >> 4;
  const int colbase = wave * 128;
  f32x4 acc[4][8] = {};

  auto stage = [&](int buf, int k0) {
    gload16(A + (m0 + wave * 16 + srow) * 512L + k0 + sg * 8, &AsB[buf][wave * 512]);
    #pragma unroll
    for (int i = 0; i < 8; ++i) {
      int c = wave * 8 + i;
      gload16(Bt + (long)(c * 16 + srow) * 512 + k0 + sg * 8, &BsB[buf][c * 512]);
    }
  };
  stage(0, 0);
  __syncthreads();
  const int kqx = (kq ^ (fr & 3)) * 8;
  for (int t = 0; t < 16; ++t) {
    int cur = t & 1;
    if (t < 15) stage(cur ^ 1, (t + 1) * 32);
    const u16* As = AsB[cur];
    const u16* Bs = BsB[cur];
    bf16x8 af[4], bfv[8];
    #pragma unroll
    for (int mi = 0; mi < 4; ++mi)
      af[mi] = *(const bf16x8*)&As[(mi * 16 + fr) * 32 + kqx];
    #pragma unroll
    for (int ni = 0; ni < 8; ++ni)
      bfv[ni] = *(const bf16x8*)&Bs[(colbase + ni * 16 + fr) * 32 + kqx];
    #pragma unroll
    for (int mi = 0; mi < 4; ++mi)
      #pragma unroll
      for (int ni = 0; ni < 8; ++ni)
        acc[mi][ni] = __builtin_amdgcn_mfma_f32_16x16x32_bf16(af[mi], bfv[ni], acc[mi][ni], 0, 0, 0);
    __syncthreads();
  }

  // --- epilogue: y = acc + bias + residual; LN over full 512-col rows ---
  float bv[8], gv[8], bb[8];
  #pragma unroll
  for (int ni = 0; ni < 8; ++ni) {
    int c = colbase + ni * 16 + fr;
    bv[ni] = bias[c]; gv[ni] = g[c]; bb[ni] = b[c];
  }
  float s16[4][4], q16[4][4];
  #pragma unroll
  for (int mi = 0; mi < 4; ++mi)
    #pragma unroll
    for (int j = 0; j < 4; ++j) {
      long row = m0 + mi * 16 + kq * 4 + j;
      float s = 0.f, sq = 0.f;
      #pragma unroll
      for (int ni = 0; ni < 8; ++ni) {
        float y = acc[mi][ni][j] + bv[ni] + xf[row * 512 + colbase + ni * 16 + fr];
        acc[mi][ni][j] = y;
        s += y; sq += y * y;
      }
      s16[mi][j] = s; q16[mi][j] = sq;
    }
  #pragma unroll
  for (int off = 1; off < 16; off <<= 1)
    #pragma unroll
    for (int mi = 0; mi < 4; ++mi)
      #pragma unroll
      for (int j = 0; j < 4; ++j) {
        s16[mi][j] += __shfl_xor(s16[mi][j], off);
        q16[mi][j] += __shfl_xor(q16[mi][j], off);
      }
  if (fr == 0) {
    #pragma unroll
    for (int mi = 0; mi < 4; ++mi)
      #pragma unroll
      for (int j = 0; j < 4; ++j) {
        int r = mi * 16 + kq * 4 + j;
        ps[wave][r][0] = s16[mi][j];
        ps[wave][r][1] = q16[mi][j];
      }
  }
  __syncthreads();
  #pragma unroll
  for (int mi = 0; mi < 4; ++mi)
    #pragma unroll
    for (int j = 0; j < 4; ++j) {
      int r = mi * 16 + kq * 4 + j;
      float S = ps[0][r][0] + ps[1][r][0] + ps[2][r][0] + ps[3][r][0];
      float Q = ps[0][r][1] + ps[1][r][1] + ps[2][r][1] + ps[3][r][1];
      float mean = S * (1.f / 512.f);
      float inv = rsqrtf(Q * (1.f / 512.f) - mean * mean + LN_EPS);
      long row = m0 + r;
      #pragma unroll
      for (int ni = 0; ni < 8; ++ni) {
        float o = (acc[mi][ni][j] - mean) * inv * gv[ni] + bb[ni];
        long idx = row * 512 + colbase + ni * 16 + fr;
        xf[idx] = o;
        xb[idx] = f2bf(o);
      }
    }
}

// ---------------------------------------------------------------------------
// MFMA attention: 1 wave per (b,head), 4 waves/block.
__global__ __launch_bounds__(256) void attn_k(const u16* __restrict__ qkv,
    const u32* __restrict__ mask, u16* __restrict__ o) {
  __shared__ u16 p_lds[4][32][40];
  int tid = threadIdx.x;
  int w = tid >> 6, lane = tid & 63;
  int idx = blockIdx.x * 4 + w;
  int b = idx >> 3, h = idx & 7;
  const u16* base = qkv + (long)b * 32 * 1536;
  int g = lane >> 4, r = lane & 15;

  f32x4 s[2][2] = {};
  #pragma unroll
  for (int ks = 0; ks < 2; ++ks) {
    bf16x8 kf[2], qf[2];
    #pragma unroll
    for (int mi = 0; mi < 2; ++mi)
      kf[mi] = *(const bf16x8*)(base + (long)(mi * 16 + r) * 1536 + 512 + h * 64 + ks * 32 + g * 8);
    #pragma unroll
    for (int nj = 0; nj < 2; ++nj)
      qf[nj] = *(const bf16x8*)(base + (long)(nj * 16 + r) * 1536 + h * 64 + ks * 32 + g * 8);
    #pragma unroll
    for (int mi = 0; mi < 2; ++mi)
      #pragma unroll
      for (int nj = 0; nj < 2; ++nj)
        s[mi][nj] = __builtin_amdgcn_mfma_f32_16x16x32_bf16(kf[mi], qf[nj], s[mi][nj], 0, 0, 0);
  }

  #pragma unroll
  for (int nj = 0; nj < 2; ++nj) {
    int q = nj * 16 + r;
    u32 mk = mask[b * 32 + q];
    float v[8];
    float mx = -1e30f;
    #pragma unroll
    for (int mi = 0; mi < 2; ++mi)
      #pragma unroll
      for (int j = 0; j < 4; ++j) {
        int k = mi * 16 + g * 4 + j;
        float val = ((mk >> k) & 1u) ? s[mi][nj][j] * ATT_SCALE : -1e30f;
        v[mi * 4 + j] = val;
        mx = fmaxf(mx, val);
      }
    mx = fmaxf(mx, __shfl_xor(mx, 16));
    mx = fmaxf(mx, __shfl_xor(mx, 32));
    float sum = 0.f;
    #pragma unroll
    for (int i = 0; i < 8; ++i) { v[i] = __expf(v[i] - mx); sum += v[i]; }
    sum += __shfl_xor(sum, 16);
    sum += __shfl_xor(sum, 32);
    float inv = 1.f / sum;
    #pragma unroll
    for (int mi = 0; mi < 2; ++mi) {
      ushort4 pk;
      pk.x = f2bf(v[mi * 4 + 0] * inv);
      pk.y = f2bf(v[mi * 4 + 1] * inv);
      pk.z = f2bf(v[mi * 4 + 2] * inv);
      pk.w = f2bf(v[mi * 4 + 3] * inv);
      *(ushort4*)&p_lds[w][q][mi * 16 + g * 4] = pk;
    }
  }
  __syncthreads();

  bf16x8 pa[2];
  #pragma unroll
  for (int mi = 0; mi < 2; ++mi)
    pa[mi] = *(const bf16x8*)&p_lds[w][mi * 16 + r][g * 8];
  f32x4 oacc[2][4] = {};
  #pragma unroll
  for (int nd = 0; nd < 4; ++nd) {
    bf16x8 vf;
    #pragma unroll
    for (int t = 0; t < 8; ++t)
      vf[t] = *(const short*)(base + (long)(g * 8 + t) * 1536 + 1024 + h * 64 + nd * 16 + r);
    #pragma unroll
    for (int mi = 0; mi < 2; ++mi)
      oacc[mi][nd] = __builtin_amdgcn_mfma_f32_16x16x32_bf16(pa[mi], vf, oacc[mi][nd], 0, 0, 0);
  }
  #pragma unroll
  for (int mi = 0; mi < 2; ++mi)
    #pragma unroll
    for (int j = 0; j < 4; ++j) {
      int q = mi * 16 + g * 4 + j;
      u16* og = o + ((long)b * 32 + q) * NHID + h * 64;
      #pragma unroll
      for (int nd = 0; nd < 4; ++nd)
        og[nd * 16 + r] = f2bf(oacc[mi][nd][j]);
    }
}

// ---------------------------------------------------------------------------
// Final FC weight transpose: W[16384][64] f32 -> Wt[sel*64 + n][16384] bf16.
__global__ __launch_bounds__(256) void fcT_k(const float* __restrict__ W1,
    const float* __restrict__ W2, u16* __restrict__ Wt) {
  __shared__ float t[64][65];
  int sel = blockIdx.y;
  const float* W = sel ? W2 : W1;
  int k0 = blockIdx.x * 64;
  int tx = threadIdx.x & 63, ty = threadIdx.x >> 6;
  #pragma unroll
  for (int i = 0; i < 16; ++i)
    t[ty + 4 * i][tx] = W[(long)(k0 + ty + 4 * i) * 64 + tx];
  __syncthreads();
  #pragma unroll
  for (int i = 0; i < 16; ++i)
    Wt[(long)(sel * 64 + ty + 4 * i) * 16384 + k0 + tx] = f2bf(t[tx][ty + 4 * i]);
}

// ---------------------------------------------------------------------------
// Final FC GEMM, K-split: part[ks][1024][128] = A[m][ks-chunk]*Wt[n][ks-chunk]^T
__global__ __launch_bounds__(256, 2) void gemm_fc(const u16* __restrict__ A,
    const u16* __restrict__ Bt, float* __restrict__ part) {
  __shared__ u16 AsB[2][128 * 32];
  __shared__ u16 BsB[2][128 * 32];
  const int tid = threadIdx.x;
  const int wave = tid >> 6, lane = tid & 63;
  const int ks = blockIdx.x;
  const long m0 = (long)blockIdx.y * 128;
  const int kbase = ks * 512;
  const int wr = wave >> 1, wc = wave & 1;
  const int srow = lane >> 2;
  const int sg = (lane & 3) ^ (srow & 3);
  const int fr = lane & 15;
  const int kq = lane >> 4;
  f32x4 acc[4][4] = {};
  auto stage = [&](int buf, int k0) {
    #pragma unroll
    for (int i = 0; i < 2; ++i) {
      int c = 2 * wave + i;
      gload16(A + (m0 + 16 * c + srow) * 16384L + kbase + k0 + sg * 8, &AsB[buf][c * 512]);
      gload16(Bt + (long)(16 * c + srow) * 16384L + kbase + k0 + sg * 8, &BsB[buf][c * 512]);
    }
  };
  stage(0, 0);
  __syncthreads();
  const int kqx = (kq ^ (fr & 3)) * 8;
  for (int t = 0; t < 16; ++t) {
    int cur = t & 1;
    if (t < 15) stage(cur ^ 1, (t + 1) * 32);
    const u16* As = AsB[cur];
    const u16* Bs = BsB[cur];
    bf16x8 af[4], bfv[4];
    #pragma unroll
    for (int mi = 0; mi < 4; ++mi)
      af[mi] = *(const bf16x8*)&As[(wr * 64 + mi * 16 + fr) * 32 + kqx];
    #pragma unroll
    for (int ni = 0; ni < 4; ++ni)
      bfv[ni] = *(const bf16x8*)&Bs[(wc * 64 + ni * 16 + fr) * 32 + kqx];
    #pragma unroll
    for (int mi = 0; mi < 4; ++mi)
      #pragma unroll
      for (int ni = 0; ni < 4; ++ni)
        acc[mi][ni] = __builtin_amdgcn_mfma_f32_16x16x32_bf16(af[mi], bfv[ni], acc[mi][ni], 0, 0, 0);
    __syncthreads();
  }
  #pragma unroll
  for (int ni = 0; ni < 4; ++ni) {
    int n = wc * 64 + ni * 16 + fr;
    #pragma unroll
    for (int mi = 0; mi < 4; ++mi) {
      long rr = m0 + wr * 64 + mi * 16 + kq * 4;
      #pragma unroll
      for (int j = 0; j < 4; ++j)
        part[((long)ks * 1024 + rr + j) * 128 + n] = acc[mi][ni][j];
    }
  }
}

__global__ __launch_bounds__(256) void fc_red_k(const float* __restrict__ part,
    const float* __restrict__ bfc1, const float* __restrict__ bfc2,
    float* __restrict__ out) {
  int idx = blockIdx.x * 256 + threadIdx.x;
  int sel = idx >> 16;
  int rem = idx & 65535;
  int b = rem >> 6, z = rem & 63;
  float v = sel ? bfc2[z] : bfc1[z];
  #pragma unroll
  for (int ks = 0; ks < 32; ++ks)
    v += part[((long)ks * 1024 + b) * 128 + sel * 64 + z];
  out[idx] = v;
}

// ---------------------------------------------------------------------------
extern "C" void kernel_launch(void* const* d_in, const int* in_sizes, int n_in,
                              void* d_out, int out_size, void* d_ws, size_t ws_size,
                              hipStream_t stream) {
  const int* node_types = (const int*)d_in[0];
  const int* adj_bits = (const int*)d_in[1];
  const float* Wpos = (const float*)d_in[2];
  const float* bpos = (const float*)d_in[3];
  const float* Wnode = (const float*)d_in[4];
  const float* bnode = (const float*)d_in[5];
  const float* eWq = (const float*)d_in[6];
  const float* eWk = (const float*)d_in[7];
  const float* eWv = (const float*)d_in[8];
  const float* eWo = (const float*)d_in[9];
  const float* eW1 = (const float*)d_in[10];
  const float* eW2 = (const float*)d_in[11];
  const float* ebq = (const float*)d_in[12];
  const float* ebk = (const float*)d_in[13];
  const float* ebv = (const float*)d_in[14];
  const float* ebo = (const float*)d_in[15];
  const float* eb1 = (const float*)d_in[16];
  const float* eb2 = (const float*)d_in[17];
  const float* ln1g = (const float*)d_in[18];
  const float* ln1b = (const float*)d_in[19];
  const float* ln2g = (const float*)d_in[20];
  const float* ln2b = (const float*)d_in[21];
  const float* Wfc1 = (const float*)d_in[22];
  const float* bfc1 = (const float*)d_in[23];
  const float* Wfc2 = (const float*)d_in[24];
  const float* bfc2 = (const float*)d_in[25];

  char* ws = (char*)d_ws;
  size_t off = 0;
  auto carve = [&](size_t bytes) {
    void* p = ws + off;
    off += (bytes + 255) & ~(size_t)255;
    return p;
  };
  u16* Wqkv_t = (u16*)carve((size_t)NLAY * 1536 * 512 * 2);
  u16* Wo_t = (u16*)carve((size_t)NLAY * 512 * 512 * 2);
  u16* W1_t = (u16*)carve((size_t)NLAY * 512 * 512 * 2);
  u16* W2_t = (u16*)carve((size_t)NLAY * 512 * 512 * 2);
  float* xf = (float*)carve((size_t)MTOT * NHID * 4);
  u16* xb = (u16*)carve((size_t)MTOT * NHID * 2);
  u16* qkv = (u16*)carve((size_t)MTOT * 1536 * 2);   // reused: Wt_fc
  u16* obuf = (u16*)carve((size_t)MTOT * NHID * 2);  // reused: hbuf, fc partials
  u32* maskb = (u32*)carve((size_t)NB * MAXN * 4);
  u16* hbuf = obuf;
  u16* Wt_fc = qkv;               // FC-time alias (qkv dead by then): 4 MB
  float* part_fc = (float*)obuf;  // FC-time alias: 32*1024*128*4 = 16.8 MB

  // --- prep ---
  mask_k<<<NB / 8, 256, 0, stream>>>(adj_bits, maskb);
  embed_k<<<(MTOT * 128) / 256, 256, 0, stream>>>(node_types, Wpos, bpos, Wnode, bnode, xf, xb);
  dim3 tg(16, 16, NLAY);
  tconv_k<<<tg, 256, 0, stream>>>(eWq, Wqkv_t, 0, 1536);
  tconv_k<<<tg, 256, 0, stream>>>(eWk, Wqkv_t, 512, 1536);
  tconv_k<<<tg, 256, 0, stream>>>(eWv, Wqkv_t, 1024, 1536);
  tconv_k<<<tg, 256, 0, stream>>>(eWo, Wo_t, 0, 512);
  tconv_k<<<tg, 256, 0, stream>>>(eW1, W1_t, 0, 512);
  tconv_k<<<tg, 256, 0, stream>>>(eW2, W2_t, 0, 512);

  // --- encoder layers ---
  for (int l = 0; l < NLAY; ++l) {
    size_t lw = (size_t)l * 512 * 512;
    gemm_bt<1><<<dim3(12, MTOT / 128), 256, 0, stream>>>(
        xb, Wqkv_t + (size_t)l * 1536 * 512,
        ebq + l * 512, ebk + l * 512, ebv + l * 512, qkv, 1536, 512);
    attn_k<<<NB * NHEAD / 4, 256, 0, stream>>>(qkv, maskb, obuf);
    gemm_ln<<<MTOT / 64, 256, 0, stream>>>(
        obuf, Wo_t + lw, ebo + l * 512, ln1g + l * 512, ln1b + l * 512, xf, xb);
    gemm_bt<2><<<dim3(4, MTOT / 128), 256, 0, stream>>>(
        xb, W1_t + lw, eb1 + l * 512, eb1 + l * 512, eb1 + l * 512, hbuf, 512, 512);
    gemm_ln<<<MTOT / 64, 256, 0, stream>>>(
        hbuf, W2_t + lw, eb2 + l * 512, ln2g + l * 512, ln2b + l * 512, xf, xb);
  }

  // --- final FC: transpose weights (into dead qkv region), K-split MFMA, reduce ---
  fcT_k<<<dim3(256, 2), 256, 0, stream>>>(Wfc1, Wfc2, Wt_fc);
  gemm_fc<<<dim3(32, 8), 256, 0, stream>>>(xb, Wt_fc, part_fc);
  fc_red_k<<<512, 256, 0, stream>>>(part_fc, bfc1, bfc2, (float*)d_out);
}

// Round 4
// 1721.734 us; speedup vs baseline: 1.1149x; 1.1149x over previous
//
#include <hip/hip_runtime.h>

// PACE DAG-transformer encoder, MI355X bf16-MFMA implementation. Round 4:
// - gemm_ln removed; residual fused into GEMM epilogue (EPI=3), LN is a
//   1-wave-per-row bf16 kernel (no LDS), f32 master dropped.
// - proper LDS swizzle ((row>>1)&3 XOR on 16B granules) -> conflict-free.
// - QKV GEMM writes V transposed (vt[b,h,d][node]) so attention PV loads
//   are 16B vectors.

typedef unsigned short u16;
typedef unsigned int u32;
typedef __attribute__((ext_vector_type(8))) short bf16x8;
typedef __attribute__((ext_vector_type(4))) float f32x4;

#define NB 1024
#define MAXN 32
#define NHID 512
#define NHEAD 8
#define NLAY 6
#define MTOT (NB * MAXN)   // 32768 rows
#define ATT_SCALE 0.125f
#define LN_EPS 1e-5f

__device__ __forceinline__ float bf2f(u16 h) { return __uint_as_float(((u32)h) << 16); }
__device__ __forceinline__ u16 f2bf(float f) {
  u32 u = __float_as_uint(f);
  return (u16)((u + 0x7fffu + ((u >> 16) & 1u)) >> 16);
}

__device__ __forceinline__ void gload16(const void* g, void* l) {
  __builtin_amdgcn_global_load_lds((const __attribute__((address_space(1))) void*)g,
                                   (__attribute__((address_space(3))) void*)l, 16, 0, 0);
}

// ---------------------------------------------------------------------------
// DAG reachability mask: per (b,q) a 32-bit "allowed key" mask.
__global__ __launch_bounds__(256) void mask_k(const int* __restrict__ adj, u32* __restrict__ mask) {
  __shared__ u32 r[8][32];
  int tid = threadIdx.x;
  int g = tid >> 5, i = tid & 31;
  int b = blockIdx.x * 8 + g;
  const int* ab = adj + ((long)b * 32 + i) * 32;
  u32 m = 0;
  for (int j = i + 1; j < 32; ++j)
    if (ab[j]) m |= (1u << j);
  r[g][i] = m;
  __syncthreads();
  for (int it = 0; it < 5; ++it) {
    u32 cur = r[g][i];
    u32 acc = cur;
    #pragma unroll
    for (int j = 0; j < 32; ++j)
      if ((cur >> j) & 1u) acc |= r[g][j];
    __syncthreads();
    r[g][i] = acc;
    __syncthreads();
  }
  u32 am = 1u << i;
  #pragma unroll
  for (int k = 0; k < 32; ++k) am |= ((r[g][k] >> i) & 1u) << k;
  mask[b * 32 + i] = am;
}

// ---------------------------------------------------------------------------
// Embedding -> xb (bf16 only).
__global__ __launch_bounds__(256) void embed_k(const int* __restrict__ types,
    const float* __restrict__ Wpos, const float* __restrict__ bpos,
    const float* __restrict__ Wnode, const float* __restrict__ bnode,
    u16* __restrict__ xb) {
  int i = blockIdx.x * 256 + threadIdx.x;
  int row = i >> 7, c = (i & 127) * 4;
  int b = row >> 5, n = row & 31;
  float v[4];
  if (c < 256) {
    int tp = types[b * 32 + n];
    const float* w = &Wnode[tp * 256 + c];
    #pragma unroll
    for (int j = 0; j < 4; ++j) v[j] = fmaxf(w[j] + bnode[c + j], 0.f);
  } else {
    int cc = c - 256;
    const float* w = &Wpos[n * 256 + cc];
    #pragma unroll
    for (int j = 0; j < 4; ++j) v[j] = w[j] + bpos[cc + j];
  }
  ushort4 h; h.x = f2bf(v[0]); h.y = f2bf(v[1]); h.z = f2bf(v[2]); h.w = f2bf(v[3]);
  *(ushort4*)&xb[(long)row * NHID + c] = h;
}

// ---------------------------------------------------------------------------
// Weight transpose + f32->bf16: W[l][k][n] -> Wt[l][n_off+n][k]
__global__ __launch_bounds__(256) void tconv_k(const float* __restrict__ W,
    u16* __restrict__ Wt, int n_off, int n_total) {
  __shared__ float tile[32][33];
  int l = blockIdx.z;
  int k0 = blockIdx.x * 32, n0 = blockIdx.y * 32;
  int tx = threadIdx.x & 31, ty = threadIdx.x >> 5;
  const float* src = W + (size_t)l * NHID * NHID;
  #pragma unroll
  for (int i = 0; i < 4; ++i)
    tile[ty + 8 * i][tx] = src[(size_t)(k0 + ty + 8 * i) * NHID + n0 + tx];
  __syncthreads();
  u16* dst = Wt + (size_t)l * n_total * NHID;
  #pragma unroll
  for (int i = 0; i < 4; ++i)
    dst[(size_t)(n_off + n0 + ty + 8 * i) * NHID + k0 + tx] = f2bf(tile[tx][ty + 8 * i]);
}

// ---------------------------------------------------------------------------
// bf16 MFMA GEMM (N=512 class): C = A*Bt^T + bias [+res] [relu].
// 128x128 tile, BK=32, dbuf LDS, conflict-free granule swizzle.
// EPI: 1 = bias; 2 = bias+relu; 3 = bias+residual(bf16)
template <int EPI>
__global__ __launch_bounds__(256, 2) void gemm_bt(
    const u16* __restrict__ A, const u16* __restrict__ Bt,
    const float* __restrict__ bias0, const u16* __restrict__ res,
    u16* __restrict__ Cout, int N, int K) {
  __shared__ u16 AsB[2][128 * 32];
  __shared__ u16 BsB[2][128 * 32];
  const int tid = threadIdx.x;
  const int wave = tid >> 6, lane = tid & 63;
  const long m0 = (long)blockIdx.y * 128;
  const int n0 = blockIdx.x * 128;
  const int wr = wave >> 1, wc = wave & 1;
  const int srow = lane >> 2;                      // row within 16-row chunk
  const int sg = (lane & 3) ^ ((srow >> 1) & 3);   // pre-swizzled src granule
  const int fr = lane & 15;
  const int kq = lane >> 4;
  f32x4 acc[4][4] = {};

  auto stage = [&](int buf, int k0) {
    #pragma unroll
    for (int i = 0; i < 2; ++i) {
      int c = 2 * wave + i;
      gload16(A + (m0 + 16 * c + srow) * (long)K + k0 + sg * 8, &AsB[buf][c * 512]);
      gload16(Bt + (long)(n0 + 16 * c + srow) * K + k0 + sg * 8, &BsB[buf][c * 512]);
    }
  };
  stage(0, 0);
  __syncthreads();
  const int nt = K >> 5;
  const int kqx = (kq ^ ((fr >> 1) & 3)) * 8;      // swizzled read granule
  for (int t = 0; t < nt; ++t) {
    int cur = t & 1;
    if (t + 1 < nt) stage(cur ^ 1, (t + 1) * 32);
    const u16* As = AsB[cur];
    const u16* Bs = BsB[cur];
    bf16x8 af[4], bfv[4];
    #pragma unroll
    for (int mi = 0; mi < 4; ++mi)
      af[mi] = *(const bf16x8*)&As[(wr * 64 + mi * 16 + fr) * 32 + kqx];
    #pragma unroll
    for (int ni = 0; ni < 4; ++ni)
      bfv[ni] = *(const bf16x8*)&Bs[(wc * 64 + ni * 16 + fr) * 32 + kqx];
    #pragma unroll
    for (int mi = 0; mi < 4; ++mi)
      #pragma unroll
      for (int ni = 0; ni < 4; ++ni)
        acc[mi][ni] = __builtin_amdgcn_mfma_f32_16x16x32_bf16(af[mi], bfv[ni], acc[mi][ni], 0, 0, 0);
    __syncthreads();
  }

  #pragma unroll
  for (int ni = 0; ni < 4; ++ni) {
    int n = n0 + wc * 64 + ni * 16 + fr;
    float bias = bias0[n];
    #pragma unroll
    for (int mi = 0; mi < 4; ++mi) {
      long r = m0 + wr * 64 + mi * 16 + kq * 4;
      #pragma unroll
      for (int j = 0; j < 4; ++j) {
        float v = acc[mi][ni][j] + bias;
        if (EPI == 2) v = fmaxf(v, 0.f);
        if (EPI == 3) v += bf2f(res[(r + j) * (long)N + n]);
        Cout[(r + j) * (long)N + n] = f2bf(v);
      }
    }
  }
}

// ---------------------------------------------------------------------------
// QKV GEMM: A[32768][512] * Wqkv_t[1536][512]^T. Q,K -> qk[row][1024]
// (packed), V -> vt[((b*8+h)*64+d)*32 + node] (transposed for attention).
__global__ __launch_bounds__(256, 2) void gemm_qkv(
    const u16* __restrict__ A, const u16* __restrict__ Bt,
    const float* __restrict__ bq, const float* __restrict__ bk,
    const float* __restrict__ bv, u16* __restrict__ qk, u16* __restrict__ vt) {
  __shared__ u16 AsB[2][128 * 32];
  __shared__ u16 BsB[2][128 * 32];
  const int tid = threadIdx.x;
  const int wave = tid >> 6, lane = tid & 63;
  const long m0 = (long)blockIdx.y * 128;
  const int n0 = blockIdx.x * 128;
  const int wr = wave >> 1, wc = wave & 1;
  const int srow = lane >> 2;
  const int sg = (lane & 3) ^ ((srow >> 1) & 3);
  const int fr = lane & 15;
  const int kq = lane >> 4;
  f32x4 acc[4][4] = {};

  auto stage = [&](int buf, int k0) {
    #pragma unroll
    for (int i = 0; i < 2; ++i) {
      int c = 2 * wave + i;
      gload16(A + (m0 + 16 * c + srow) * 512L + k0 + sg * 8, &AsB[buf][c * 512]);
      gload16(Bt + (long)(n0 + 16 * c + srow) * 512 + k0 + sg * 8, &BsB[buf][c * 512]);
    }
  };
  stage(0, 0);
  __syncthreads();
  const int kqx = (kq ^ ((fr >> 1) & 3)) * 8;
  for (int t = 0; t < 16; ++t) {
    int cur = t & 1;
    if (t < 15) stage(cur ^ 1, (t + 1) * 32);
    const u16* As = AsB[cur];
    const u16* Bs = BsB[cur];
    bf16x8 af[4], bfv[4];
    #pragma unroll
    for (int mi = 0; mi < 4; ++mi)
      af[mi] = *(const bf16x8*)&As[(wr * 64 + mi * 16 + fr) * 32 + kqx];
    #pragma unroll
    for (int ni = 0; ni < 4; ++ni)
      bfv[ni] = *(const bf16x8*)&Bs[(wc * 64 + ni * 16 + fr) * 32 + kqx];
    #pragma unroll
    for (int mi = 0; mi < 4; ++mi)
      #pragma unroll
      for (int ni = 0; ni < 4; ++ni)
        acc[mi][ni] = __builtin_amdgcn_mfma_f32_16x16x32_bf16(af[mi], bfv[ni], acc[mi][ni], 0, 0, 0);
    __syncthreads();
  }

  #pragma unroll
  for (int ni = 0; ni < 4; ++ni) {
    int n = n0 + wc * 64 + ni * 16 + fr;
    float bias = (n < 512) ? bq[n] : ((n < 1024) ? bk[n - 512] : bv[n - 1024]);
    bool isv = (n >= 1024);
    long vcol = isv ? (long)(n - 1024) * 32 : 0;   // (h*64+d)*32
    #pragma unroll
    for (int mi = 0; mi < 4; ++mi) {
      long r = m0 + wr * 64 + mi * 16 + kq * 4;
      #pragma unroll
      for (int j = 0; j < 4; ++j) {
        u16 hv = f2bf(acc[mi][ni][j] + bias);
        long rr = r + j;
        if (!isv) qk[rr * 1024 + n] = hv;
        else      vt[(rr >> 5) * 16384 + vcol + (rr & 31)] = hv;
      }
    }
  }
}

// ---------------------------------------------------------------------------
// MFMA attention: 1 wave per (b,head), 4 waves/block; fully vectorized loads.
__global__ __launch_bounds__(256) void attn_k(const u16* __restrict__ qk,
    const u16* __restrict__ vt, const u32* __restrict__ mask, u16* __restrict__ o) {
  __shared__ u16 p_lds[4][32][40];
  int tid = threadIdx.x;
  int w = tid >> 6, lane = tid & 63;
  int idx = blockIdx.x * 4 + w;
  int b = idx >> 3, h = idx & 7;
  const u16* qbase = qk + (long)b * 32 * 1024 + h * 64;
  const u16* kbase = qbase + 512;
  int g = lane >> 4, r = lane & 15;

  // --- S^T = K · Q^T ---
  f32x4 s[2][2] = {};
  #pragma unroll
  for (int ks = 0; ks < 2; ++ks) {
    bf16x8 kf[2], qf[2];
    #pragma unroll
    for (int mi = 0; mi < 2; ++mi)
      kf[mi] = *(const bf16x8*)(kbase + (long)(mi * 16 + r) * 1024 + ks * 32 + g * 8);
    #pragma unroll
    for (int nj = 0; nj < 2; ++nj)
      qf[nj] = *(const bf16x8*)(qbase + (long)(nj * 16 + r) * 1024 + ks * 32 + g * 8);
    #pragma unroll
    for (int mi = 0; mi < 2; ++mi)
      #pragma unroll
      for (int nj = 0; nj < 2; ++nj)
        s[mi][nj] = __builtin_amdgcn_mfma_f32_16x16x32_bf16(kf[mi], qf[nj], s[mi][nj], 0, 0, 0);
  }

  // --- masked softmax per query column ---
  #pragma unroll
  for (int nj = 0; nj < 2; ++nj) {
    int q = nj * 16 + r;
    u32 mk = mask[b * 32 + q];
    float v[8];
    float mx = -1e30f;
    #pragma unroll
    for (int mi = 0; mi < 2; ++mi)
      #pragma unroll
      for (int j = 0; j < 4; ++j) {
        int k = mi * 16 + g * 4 + j;
        float val = ((mk >> k) & 1u) ? s[mi][nj][j] * ATT_SCALE : -1e30f;
        v[mi * 4 + j] = val;
        mx = fmaxf(mx, val);
      }
    mx = fmaxf(mx, __shfl_xor(mx, 16));
    mx = fmaxf(mx, __shfl_xor(mx, 32));
    float sum = 0.f;
    #pragma unroll
    for (int i = 0; i < 8; ++i) { v[i] = __expf(v[i] - mx); sum += v[i]; }
    sum += __shfl_xor(sum, 16);
    sum += __shfl_xor(sum, 32);
    float inv = 1.f / sum;
    #pragma unroll
    for (int mi = 0; mi < 2; ++mi) {
      ushort4 pk;
      pk.x = f2bf(v[mi * 4 + 0] * inv);
      pk.y = f2bf(v[mi * 4 + 1] * inv);
      pk.z = f2bf(v[mi * 4 + 2] * inv);
      pk.w = f2bf(v[mi * 4 + 3] * inv);
      *(ushort4*)&p_lds[w][q][mi * 16 + g * 4] = pk;
    }
  }
  __syncthreads();

  // --- O = P · V, V from transposed vt (16B vector loads) ---
  bf16x8 pa[2];
  #pragma unroll
  for (int mi = 0; mi < 2; ++mi)
    pa[mi] = *(const bf16x8*)&p_lds[w][mi * 16 + r][g * 8];
  const u16* vbase = vt + (long)(b * 8 + h) * 64 * 32;
  f32x4 oacc[2][4] = {};
  #pragma unroll
  for (int nd = 0; nd < 4; ++nd) {
    bf16x8 vf = *(const bf16x8*)(vbase + (nd * 16 + r) * 32 + g * 8);
    #pragma unroll
    for (int mi = 0; mi < 2; ++mi)
      oacc[mi][nd] = __builtin_amdgcn_mfma_f32_16x16x32_bf16(pa[mi], vf, oacc[mi][nd], 0, 0, 0);
  }
  #pragma unroll
  for (int mi = 0; mi < 2; ++mi)
    #pragma unroll
    for (int j = 0; j < 4; ++j) {
      int q = mi * 16 + g * 4 + j;
      u16* og = o + ((long)b * 32 + q) * NHID + h * 64;
      #pragma unroll
      for (int nd = 0; nd < 4; ++nd)
        og[nd * 16 + r] = f2bf(oacc[mi][nd][j]);
    }
}

// ---------------------------------------------------------------------------
// LayerNorm: xb = LN(y)*g + b. 1 wave per 512-col row, bf16 in/out, no LDS.
__global__ __launch_bounds__(256) void ln_k(const u16* __restrict__ y,
    const float* __restrict__ g, const float* __restrict__ b, u16* __restrict__ xb) {
  int tid = threadIdx.x;
  int w = tid >> 6, lane = tid & 63;
  long row = (long)blockIdx.x * 4 + w;
  int c = lane * 8;
  long o = row * NHID + c;
  ushort4 a0 = *(const ushort4*)&y[o];
  ushort4 a1 = *(const ushort4*)&y[o + 4];
  float v[8] = {bf2f(a0.x), bf2f(a0.y), bf2f(a0.z), bf2f(a0.w),
                bf2f(a1.x), bf2f(a1.y), bf2f(a1.z), bf2f(a1.w)};
  float s = 0.f, sq = 0.f;
  #pragma unroll
  for (int j = 0; j < 8; ++j) { s += v[j]; sq += v[j] * v[j]; }
  #pragma unroll
  for (int off = 1; off < 64; off <<= 1) {
    s += __shfl_xor(s, off);
    sq += __shfl_xor(sq, off);
  }
  float mean = s * (1.f / 512.f);
  float inv = rsqrtf(sq * (1.f / 512.f) - mean * mean + LN_EPS);
  float4 ga = *(const float4*)&g[c], gb = *(const float4*)&g[c + 4];
  float4 ba = *(const float4*)&b[c], bb = *(const float4*)&b[c + 4];
  float gg[8] = {ga.x, ga.y, ga.z, ga.w, gb.x, gb.y, gb.z, gb.w};
  float bv[8] = {ba.x, ba.y, ba.z, ba.w, bb.x, bb.y, bb.z, bb.w};
  ushort4 o0, o1;
  o0.x = f2bf((v[0] - mean) * inv * gg[0] + bv[0]);
  o0.y = f2bf((v[1] - mean) * inv * gg[1] + bv[1]);
  o0.z = f2bf((v[2] - mean) * inv * gg[2] + bv[2]);
  o0.w = f2bf((v[3] - mean) * inv * gg[3] + bv[3]);
  o1.x = f2bf((v[4] - mean) * inv * gg[4] + bv[4]);
  o1.y = f2bf((v[5] - mean) * inv * gg[5] + bv[5]);
  o1.z = f2bf((v[6] - mean) * inv * gg[6] + bv[6]);
  o1.w = f2bf((v[7] - mean) * inv * gg[7] + bv[7]);
  *(ushort4*)&xb[o] = o0;
  *(ushort4*)&xb[o + 4] = o1;
}

// ---------------------------------------------------------------------------
// Final FC weight transpose: W[16384][64] f32 -> Wt[sel*64 + n][16384] bf16.
__global__ __launch_bounds__(256) void fcT_k(const float* __restrict__ W1,
    const float* __restrict__ W2, u16* __restrict__ Wt) {
  __shared__ float t[64][65];
  int sel = blockIdx.y;
  const float* W = sel ? W2 : W1;
  int k0 = blockIdx.x * 64;
  int tx = threadIdx.x & 63, ty = threadIdx.x >> 6;
  #pragma unroll
  for (int i = 0; i < 16; ++i)
    t[ty + 4 * i][tx] = W[(long)(k0 + ty + 4 * i) * 64 + tx];
  __syncthreads();
  #pragma unroll
  for (int i = 0; i < 16; ++i)
    Wt[(long)(sel * 64 + ty + 4 * i) * 16384 + k0 + tx] = f2bf(t[tx][ty + 4 * i]);
}

// ---------------------------------------------------------------------------
// Final FC GEMM, K-split: part[ks][1024][128] = A[m][ks-chunk]*Wt[n][ks-chunk]^T
__global__ __launch_bounds__(256, 2) void gemm_fc(const u16* __restrict__ A,
    const u16* __restrict__ Bt, float* __restrict__ part) {
  __shared__ u16 AsB[2][128 * 32];
  __shared__ u16 BsB[2][128 * 32];
  const int tid = threadIdx.x;
  const int wave = tid >> 6, lane = tid & 63;
  const int ks = blockIdx.x;
  const long m0 = (long)blockIdx.y * 128;
  const int kbase = ks * 512;
  const int wr = wave >> 1, wc = wave & 1;
  const int srow = lane >> 2;
  const int sg = (lane & 3) ^ ((srow >> 1) & 3);
  const int fr = lane & 15;
  const int kq = lane >> 4;
  f32x4 acc[4][4] = {};
  auto stage = [&](int buf, int k0) {
    #pragma unroll
    for (int i = 0; i < 2; ++i) {
      int c = 2 * wave + i;
      gload16(A + (m0 + 16 * c + srow) * 16384L + kbase + k0 + sg * 8, &AsB[buf][c * 512]);
      gload16(Bt + (long)(16 * c + srow) * 16384L + kbase + k0 + sg * 8, &BsB[buf][c * 512]);
    }
  };
  stage(0, 0);
  __syncthreads();
  const int kqx = (kq ^ ((fr >> 1) & 3)) * 8;
  for (int t = 0; t < 16; ++t) {
    int cur = t & 1;
    if (t < 15) stage(cur ^ 1, (t + 1) * 32);
    const u16* As = AsB[cur];
    const u16* Bs = BsB[cur];
    bf16x8 af[4], bfv[4];
    #pragma unroll
    for (int mi = 0; mi < 4; ++mi)
      af[mi] = *(const bf16x8*)&As[(wr * 64 + mi * 16 + fr) * 32 + kqx];
    #pragma unroll
    for (int ni = 0; ni < 4; ++ni)
      bfv[ni] = *(const bf16x8*)&Bs[(wc * 64 + ni * 16 + fr) * 32 + kqx];
    #pragma unroll
    for (int mi = 0; mi < 4; ++mi)
      #pragma unroll
      for (int ni = 0; ni < 4; ++ni)
        acc[mi][ni] = __builtin_amdgcn_mfma_f32_16x16x32_bf16(af[mi], bfv[ni], acc[mi][ni], 0, 0, 0);
    __syncthreads();
  }
  #pragma unroll
  for (int ni = 0; ni < 4; ++ni) {
    int n = wc * 64 + ni * 16 + fr;
    #pragma unroll
    for (int mi = 0; mi < 4; ++mi) {
      long rr = m0 + wr * 64 + mi * 16 + kq * 4;
      #pragma unroll
      for (int j = 0; j < 4; ++j)
        part[((long)ks * 1024 + rr + j) * 128 + n] = acc[mi][ni][j];
    }
  }
}

__global__ __launch_bounds__(256) void fc_red_k(const float* __restrict__ part,
    const float* __restrict__ bfc1, const float* __restrict__ bfc2,
    float* __restrict__ out) {
  int idx = blockIdx.x * 256 + threadIdx.x;
  int sel = idx >> 16;
  int rem = idx & 65535;
  int b = rem >> 6, z = rem & 63;
  float v = sel ? bfc2[z] : bfc1[z];
  #pragma unroll
  for (int ks = 0; ks < 32; ++ks)
    v += part[((long)ks * 1024 + b) * 128 + sel * 64 + z];
  out[idx] = v;
}

// ---------------------------------------------------------------------------
extern "C" void kernel_launch(void* const* d_in, const int* in_sizes, int n_in,
                              void* d_out, int out_size, void* d_ws, size_t ws_size,
                              hipStream_t stream) {
  const int* node_types = (const int*)d_in[0];
  const int* adj_bits = (const int*)d_in[1];
  const float* Wpos = (const float*)d_in[2];
  const float* bpos = (const float*)d_in[3];
  const float* Wnode = (const float*)d_in[4];
  const float* bnode = (const float*)d_in[5];
  const float* eWq = (const float*)d_in[6];
  const float* eWk = (const float*)d_in[7];
  const float* eWv = (const float*)d_in[8];
  const float* eWo = (const float*)d_in[9];
  const float* eW1 = (const float*)d_in[10];
  const float* eW2 = (const float*)d_in[11];
  const float* ebq = (const float*)d_in[12];
  const float* ebk = (const float*)d_in[13];
  const float* ebv = (const float*)d_in[14];
  const float* ebo = (const float*)d_in[15];
  const float* eb1 = (const float*)d_in[16];
  const float* eb2 = (const float*)d_in[17];
  const float* ln1g = (const float*)d_in[18];
  const float* ln1b = (const float*)d_in[19];
  const float* ln2g = (const float*)d_in[20];
  const float* ln2b = (const float*)d_in[21];
  const float* Wfc1 = (const float*)d_in[22];
  const float* bfc1 = (const float*)d_in[23];
  const float* Wfc2 = (const float*)d_in[24];
  const float* bfc2 = (const float*)d_in[25];

  char* ws = (char*)d_ws;
  size_t off = 0;
  auto carve = [&](size_t bytes) {
    void* p = ws + off;
    off += (bytes + 255) & ~(size_t)255;
    return p;
  };
  u16* Wqkv_t = (u16*)carve((size_t)NLAY * 1536 * 512 * 2);
  u16* Wo_t = (u16*)carve((size_t)NLAY * 512 * 512 * 2);
  u16* W1_t = (u16*)carve((size_t)NLAY * 512 * 512 * 2);
  u16* W2_t = (u16*)carve((size_t)NLAY * 512 * 512 * 2);
  u16* xb = (u16*)carve((size_t)MTOT * NHID * 2);       // 32 MB: layer state
  u16* qk = (u16*)carve((size_t)MTOT * 1024 * 2);       // 64 MB: Q,K / ybuf / Wt_fc
  u16* vt = (u16*)carve((size_t)MTOT * NHID * 2);       // 32 MB: V transposed
  u16* obuf = (u16*)carve((size_t)MTOT * NHID * 2);     // 32 MB: attn out / hbuf / part
  u32* maskb = (u32*)carve((size_t)NB * MAXN * 4);
  u16* ybuf = qk;                 // pre-LN y (qk dead after attn)
  u16* hbuf = obuf;               // MLP hidden
  u16* Wt_fc = qk;                // FC-time alias: 4 MB
  float* part_fc = (float*)obuf;  // FC-time alias: 16.8 MB

  // --- prep ---
  mask_k<<<NB / 8, 256, 0, stream>>>(adj_bits, maskb);
  embed_k<<<(MTOT * 128) / 256, 256, 0, stream>>>(node_types, Wpos, bpos, Wnode, bnode, xb);
  dim3 tg(16, 16, NLAY);
  tconv_k<<<tg, 256, 0, stream>>>(eWq, Wqkv_t, 0, 1536);
  tconv_k<<<tg, 256, 0, stream>>>(eWk, Wqkv_t, 512, 1536);
  tconv_k<<<tg, 256, 0, stream>>>(eWv, Wqkv_t, 1024, 1536);
  tconv_k<<<tg, 256, 0, stream>>>(eWo, Wo_t, 0, 512);
  tconv_k<<<tg, 256, 0, stream>>>(eW1, W1_t, 0, 512);
  tconv_k<<<tg, 256, 0, stream>>>(eW2, W2_t, 0, 512);

  // --- encoder layers ---
  for (int l = 0; l < NLAY; ++l) {
    size_t lw = (size_t)l * 512 * 512;
    gemm_qkv<<<dim3(12, MTOT / 128), 256, 0, stream>>>(
        xb, Wqkv_t + (size_t)l * 1536 * 512,
        ebq + l * 512, ebk + l * 512, ebv + l * 512, qk, vt);
    attn_k<<<NB * NHEAD / 4, 256, 0, stream>>>(qk, vt, maskb, obuf);
    gemm_bt<3><<<dim3(4, MTOT / 128), 256, 0, stream>>>(
        obuf, Wo_t + lw, ebo + l * 512, xb, ybuf, 512, 512);
    ln_k<<<MTOT / 4, 256, 0, stream>>>(ybuf, ln1g + l * 512, ln1b + l * 512, xb);
    gemm_bt<2><<<dim3(4, MTOT / 128), 256, 0, stream>>>(
        xb, W1_t + lw, eb1 + l * 512, nullptr, hbuf, 512, 512);
    gemm_bt<3><<<dim3(4, MTOT / 128), 256, 0, stream>>>(
        hbuf, W2_t + lw, eb2 + l * 512, xb, ybuf, 512, 512);
    ln_k<<<MTOT / 4, 256, 0, stream>>>(ybuf, ln2g + l * 512, ln2b + l * 512, xb);
  }

  // --- final FC: transpose weights (dead qk region), K-split MFMA, reduce ---
  fcT_k<<<dim3(256, 2), 256, 0, stream>>>(Wfc1, Wfc2, Wt_fc);
  gemm_fc<<<dim3(32, 8), 256, 0, stream>>>(xb, Wt_fc, part_fc);
  fc_red_k<<<512, 256, 0, stream>>>(part_fc, bfc1, bfc2, (float*)d_out);
}

// Round 5
// 1644.726 us; speedup vs baseline: 1.1671x; 1.0468x over previous
//
#include <hip/hip_runtime.h>

// PACE DAG-transformer encoder, MI355X bf16-MFMA implementation. Round 5:
// - GEMMs back to single-buffer 2-barrier K-loop (dbuf cost occupancy with
//   zero overlap gain: measured 92->132us regression in r4).
// - Keep conflict-free LDS granule swizzle (r4: bank conflicts -> 0).
// - XCD-aware block remap in gemm_bt/gemm_qkv: all n-blocks of one A-panel
//   run on one XCD -> A fetched from HBM once (FETCH 138MB -> ~45MB).

typedef unsigned short u16;
typedef unsigned int u32;
typedef __attribute__((ext_vector_type(8))) short bf16x8;
typedef __attribute__((ext_vector_type(4))) float f32x4;

#define NB 1024
#define MAXN 32
#define NHID 512
#define NHEAD 8
#define NLAY 6
#define MTOT (NB * MAXN)   // 32768 rows
#define ATT_SCALE 0.125f
#define LN_EPS 1e-5f

__device__ __forceinline__ float bf2f(u16 h) { return __uint_as_float(((u32)h) << 16); }
__device__ __forceinline__ u16 f2bf(float f) {
  u32 u = __float_as_uint(f);
  return (u16)((u + 0x7fffu + ((u >> 16) & 1u)) >> 16);
}

__device__ __forceinline__ void gload16(const void* g, void* l) {
  __builtin_amdgcn_global_load_lds((const __attribute__((address_space(1))) void*)g,
                                   (__attribute__((address_space(3))) void*)l, 16, 0, 0);
}

// XCD-aware remap: linear id l -> (m-tile, n-tile) such that all NX blocks
// of one m-panel run on the same XCD (l%8 assumed XCD round-robin; perf-only).
__device__ __forceinline__ void xcd_remap(int l, int NX, int& mt, int& nt) {
  int xcd = l & 7;
  int s = l >> 3;
  int mg = s / NX;
  nt = s - mg * NX;
  mt = mg * 8 + xcd;
}

// ---------------------------------------------------------------------------
// DAG reachability mask: per (b,q) a 32-bit "allowed key" mask.
__global__ __launch_bounds__(256) void mask_k(const int* __restrict__ adj, u32* __restrict__ mask) {
  __shared__ u32 r[8][32];
  int tid = threadIdx.x;
  int g = tid >> 5, i = tid & 31;
  int b = blockIdx.x * 8 + g;
  const int* ab = adj + ((long)b * 32 + i) * 32;
  u32 m = 0;
  for (int j = i + 1; j < 32; ++j)
    if (ab[j]) m |= (1u << j);
  r[g][i] = m;
  __syncthreads();
  for (int it = 0; it < 5; ++it) {
    u32 cur = r[g][i];
    u32 acc = cur;
    #pragma unroll
    for (int j = 0; j < 32; ++j)
      if ((cur >> j) & 1u) acc |= r[g][j];
    __syncthreads();
    r[g][i] = acc;
    __syncthreads();
  }
  u32 am = 1u << i;
  #pragma unroll
  for (int k = 0; k < 32; ++k) am |= ((r[g][k] >> i) & 1u) << k;
  mask[b * 32 + i] = am;
}

// ---------------------------------------------------------------------------
// Embedding -> xb (bf16 only).
__global__ __launch_bounds__(256) void embed_k(const int* __restrict__ types,
    const float* __restrict__ Wpos, const float* __restrict__ bpos,
    const float* __restrict__ Wnode, const float* __restrict__ bnode,
    u16* __restrict__ xb) {
  int i = blockIdx.x * 256 + threadIdx.x;
  int row = i >> 7, c = (i & 127) * 4;
  int b = row >> 5, n = row & 31;
  float v[4];
  if (c < 256) {
    int tp = types[b * 32 + n];
    const float* w = &Wnode[tp * 256 + c];
    #pragma unroll
    for (int j = 0; j < 4; ++j) v[j] = fmaxf(w[j] + bnode[c + j], 0.f);
  } else {
    int cc = c - 256;
    const float* w = &Wpos[n * 256 + cc];
    #pragma unroll
    for (int j = 0; j < 4; ++j) v[j] = w[j] + bpos[cc + j];
  }
  ushort4 h; h.x = f2bf(v[0]); h.y = f2bf(v[1]); h.z = f2bf(v[2]); h.w = f2bf(v[3]);
  *(ushort4*)&xb[(long)row * NHID + c] = h;
}

// ---------------------------------------------------------------------------
// Weight transpose + f32->bf16: W[l][k][n] -> Wt[l][n_off+n][k]
__global__ __launch_bounds__(256) void tconv_k(const float* __restrict__ W,
    u16* __restrict__ Wt, int n_off, int n_total) {
  __shared__ float tile[32][33];
  int l = blockIdx.z;
  int k0 = blockIdx.x * 32, n0 = blockIdx.y * 32;
  int tx = threadIdx.x & 31, ty = threadIdx.x >> 5;
  const float* src = W + (size_t)l * NHID * NHID;
  #pragma unroll
  for (int i = 0; i < 4; ++i)
    tile[ty + 8 * i][tx] = src[(size_t)(k0 + ty + 8 * i) * NHID + n0 + tx];
  __syncthreads();
  u16* dst = Wt + (size_t)l * n_total * NHID;
  #pragma unroll
  for (int i = 0; i < 4; ++i)
    dst[(size_t)(n_off + n0 + ty + 8 * i) * NHID + k0 + tx] = f2bf(tile[tx][ty + 8 * i]);
}

// ---------------------------------------------------------------------------
// bf16 MFMA GEMM (N=512 class): C = A*Bt^T + bias [+res] [relu].
// 128x128 tile, BK=32, single-buffer LDS, conflict-free swizzle, XCD remap.
// EPI: 1 = bias; 2 = bias+relu; 3 = bias+residual(bf16)
template <int EPI>
__global__ __launch_bounds__(256, 2) void gemm_bt(
    const u16* __restrict__ A, const u16* __restrict__ Bt,
    const float* __restrict__ bias0, const u16* __restrict__ res,
    u16* __restrict__ Cout, int N, int K) {
  __shared__ u16 As[128 * 32];
  __shared__ u16 Bs[128 * 32];
  const int tid = threadIdx.x;
  const int wave = tid >> 6, lane = tid & 63;
  int mt, nt;
  xcd_remap(blockIdx.x + gridDim.x * blockIdx.y, gridDim.x, mt, nt);
  const long m0 = (long)mt * 128;
  const int n0 = nt * 128;
  const int wr = wave >> 1, wc = wave & 1;
  const int srow = lane >> 2;
  const int sg = (lane & 3) ^ ((srow >> 1) & 3);   // pre-swizzled src granule
  const int fr = lane & 15;
  const int kq = lane >> 4;
  f32x4 acc[4][4] = {};

  const int kqx = (kq ^ ((fr >> 1) & 3)) * 8;      // swizzled read granule
  for (int k0 = 0; k0 < K; k0 += 32) {
    #pragma unroll
    for (int i = 0; i < 2; ++i) {
      int c = 2 * wave + i;
      gload16(A + (m0 + 16 * c + srow) * (long)K + k0 + sg * 8, &As[c * 512]);
      gload16(Bt + (long)(n0 + 16 * c + srow) * K + k0 + sg * 8, &Bs[c * 512]);
    }
    __syncthreads();
    bf16x8 af[4], bfv[4];
    #pragma unroll
    for (int mi = 0; mi < 4; ++mi)
      af[mi] = *(const bf16x8*)&As[(wr * 64 + mi * 16 + fr) * 32 + kqx];
    #pragma unroll
    for (int ni = 0; ni < 4; ++ni)
      bfv[ni] = *(const bf16x8*)&Bs[(wc * 64 + ni * 16 + fr) * 32 + kqx];
    #pragma unroll
    for (int mi = 0; mi < 4; ++mi)
      #pragma unroll
      for (int ni = 0; ni < 4; ++ni)
        acc[mi][ni] = __builtin_amdgcn_mfma_f32_16x16x32_bf16(af[mi], bfv[ni], acc[mi][ni], 0, 0, 0);
    __syncthreads();
  }

  #pragma unroll
  for (int ni = 0; ni < 4; ++ni) {
    int n = n0 + wc * 64 + ni * 16 + fr;
    float bias = bias0[n];
    #pragma unroll
    for (int mi = 0; mi < 4; ++mi) {
      long r = m0 + wr * 64 + mi * 16 + kq * 4;
      #pragma unroll
      for (int j = 0; j < 4; ++j) {
        float v = acc[mi][ni][j] + bias;
        if (EPI == 2) v = fmaxf(v, 0.f);
        if (EPI == 3) v += bf2f(res[(r + j) * (long)N + n]);
        Cout[(r + j) * (long)N + n] = f2bf(v);
      }
    }
  }
}

// ---------------------------------------------------------------------------
// QKV GEMM: A[32768][512] * Wqkv_t[1536][512]^T. Q,K -> qk[row][1024]
// (packed), V -> vt[((b*8+h)*64+d)*32 + node] (transposed for attention).
__global__ __launch_bounds__(256, 2) void gemm_qkv(
    const u16* __restrict__ A, const u16* __restrict__ Bt,
    const float* __restrict__ bq, const float* __restrict__ bk,
    const float* __restrict__ bv, u16* __restrict__ qk, u16* __restrict__ vt) {
  __shared__ u16 As[128 * 32];
  __shared__ u16 Bs[128 * 32];
  const int tid = threadIdx.x;
  const int wave = tid >> 6, lane = tid & 63;
  int mt, nt;
  xcd_remap(blockIdx.x + gridDim.x * blockIdx.y, gridDim.x, mt, nt);
  const long m0 = (long)mt * 128;
  const int n0 = nt * 128;
  const int wr = wave >> 1, wc = wave & 1;
  const int srow = lane >> 2;
  const int sg = (lane & 3) ^ ((srow >> 1) & 3);
  const int fr = lane & 15;
  const int kq = lane >> 4;
  f32x4 acc[4][4] = {};

  const int kqx = (kq ^ ((fr >> 1) & 3)) * 8;
  for (int k0 = 0; k0 < 512; k0 += 32) {
    #pragma unroll
    for (int i = 0; i < 2; ++i) {
      int c = 2 * wave + i;
      gload16(A + (m0 + 16 * c + srow) * 512L + k0 + sg * 8, &As[c * 512]);
      gload16(Bt + (long)(n0 + 16 * c + srow) * 512 + k0 + sg * 8, &Bs[c * 512]);
    }
    __syncthreads();
    bf16x8 af[4], bfv[4];
    #pragma unroll
    for (int mi = 0; mi < 4; ++mi)
      af[mi] = *(const bf16x8*)&As[(wr * 64 + mi * 16 + fr) * 32 + kqx];
    #pragma unroll
    for (int ni = 0; ni < 4; ++ni)
      bfv[ni] = *(const bf16x8*)&Bs[(wc * 64 + ni * 16 + fr) * 32 + kqx];
    #pragma unroll
    for (int mi = 0; mi < 4; ++mi)
      #pragma unroll
      for (int ni = 0; ni < 4; ++ni)
        acc[mi][ni] = __builtin_amdgcn_mfma_f32_16x16x32_bf16(af[mi], bfv[ni], acc[mi][ni], 0, 0, 0);
    __syncthreads();
  }

  #pragma unroll
  for (int ni = 0; ni < 4; ++ni) {
    int n = n0 + wc * 64 + ni * 16 + fr;
    float bias = (n < 512) ? bq[n] : ((n < 1024) ? bk[n - 512] : bv[n - 1024]);
    bool isv = (n >= 1024);
    long vcol = isv ? (long)(n - 1024) * 32 : 0;   // (h*64+d)*32
    #pragma unroll
    for (int mi = 0; mi < 4; ++mi) {
      long r = m0 + wr * 64 + mi * 16 + kq * 4;
      #pragma unroll
      for (int j = 0; j < 4; ++j) {
        u16 hv = f2bf(acc[mi][ni][j] + bias);
        long rr = r + j;
        if (!isv) qk[rr * 1024 + n] = hv;
        else      vt[(rr >> 5) * 16384 + vcol + (rr & 31)] = hv;
      }
    }
  }
}

// ---------------------------------------------------------------------------
// MFMA attention: 1 wave per (b,head), 4 waves/block; fully vectorized loads.
__global__ __launch_bounds__(256) void attn_k(const u16* __restrict__ qk,
    const u16* __restrict__ vt, const u32* __restrict__ mask, u16* __restrict__ o) {
  __shared__ u16 p_lds[4][32][40];
  int tid = threadIdx.x;
  int w = tid >> 6, lane = tid & 63;
  int idx = blockIdx.x * 4 + w;
  int b = idx >> 3, h = idx & 7;
  const u16* qbase = qk + (long)b * 32 * 1024 + h * 64;
  const u16* kbase = qbase + 512;
  int g = lane >> 4, r = lane & 15;

  // --- S^T = K · Q^T ---
  f32x4 s[2][2] = {};
  #pragma unroll
  for (int ks = 0; ks < 2; ++ks) {
    bf16x8 kf[2], qf[2];
    #pragma unroll
    for (int mi = 0; mi < 2; ++mi)
      kf[mi] = *(const bf16x8*)(kbase + (long)(mi * 16 + r) * 1024 + ks * 32 + g * 8);
    #pragma unroll
    for (int nj = 0; nj < 2; ++nj)
      qf[nj] = *(const bf16x8*)(qbase + (long)(nj * 16 + r) * 1024 + ks * 32 + g * 8);
    #pragma unroll
    for (int mi = 0; mi < 2; ++mi)
      #pragma unroll
      for (int nj = 0; nj < 2; ++nj)
        s[mi][nj] = __builtin_amdgcn_mfma_f32_16x16x32_bf16(kf[mi], qf[nj], s[mi][nj], 0, 0, 0);
  }

  // --- masked softmax per query column ---
  #pragma unroll
  for (int nj = 0; nj < 2; ++nj) {
    int q = nj * 16 + r;
    u32 mk = mask[b * 32 + q];
    float v[8];
    float mx = -1e30f;
    #pragma unroll
    for (int mi = 0; mi < 2; ++mi)
      #pragma unroll
      for (int j = 0; j < 4; ++j) {
        int k = mi * 16 + g * 4 + j;
        float val = ((mk >> k) & 1u) ? s[mi][nj][j] * ATT_SCALE : -1e30f;
        v[mi * 4 + j] = val;
        mx = fmaxf(mx, val);
      }
    mx = fmaxf(mx, __shfl_xor(mx, 16));
    mx = fmaxf(mx, __shfl_xor(mx, 32));
    float sum = 0.f;
    #pragma unroll
    for (int i = 0; i < 8; ++i) { v[i] = __expf(v[i] - mx); sum += v[i]; }
    sum += __shfl_xor(sum, 16);
    sum += __shfl_xor(sum, 32);
    float inv = 1.f / sum;
    #pragma unroll
    for (int mi = 0; mi < 2; ++mi) {
      ushort4 pk;
      pk.x = f2bf(v[mi * 4 + 0] * inv);
      pk.y = f2bf(v[mi * 4 + 1] * inv);
      pk.z = f2bf(v[mi * 4 + 2] * inv);
      pk.w = f2bf(v[mi * 4 + 3] * inv);
      *(ushort4*)&p_lds[w][q][mi * 16 + g * 4] = pk;
    }
  }
  __syncthreads();

  // --- O = P · V, V from transposed vt (16B vector loads) ---
  bf16x8 pa[2];
  #pragma unroll
  for (int mi = 0; mi < 2; ++mi)
    pa[mi] = *(const bf16x8*)&p_lds[w][mi * 16 + r][g * 8];
  const u16* vbase = vt + (long)(b * 8 + h) * 64 * 32;
  f32x4 oacc[2][4] = {};
  #pragma unroll
  for (int nd = 0; nd < 4; ++nd) {
    bf16x8 vf = *(const bf16x8*)(vbase + (nd * 16 + r) * 32 + g * 8);
    #pragma unroll
    for (int mi = 0; mi < 2; ++mi)
      oacc[mi][nd] = __builtin_amdgcn_mfma_f32_16x16x32_bf16(pa[mi], vf, oacc[mi][nd], 0, 0, 0);
  }
  #pragma unroll
  for (int mi = 0; mi < 2; ++mi)
    #pragma unroll
    for (int j = 0; j < 4; ++j) {
      int q = mi * 16 + g * 4 + j;
      u16* og = o + ((long)b * 32 + q) * NHID + h * 64;
      #pragma unroll
      for (int nd = 0; nd < 4; ++nd)
        og[nd * 16 + r] = f2bf(oacc[mi][nd][j]);
    }
}

// ---------------------------------------------------------------------------
// LayerNorm: xb = LN(y)*g + b. 1 wave per 512-col row, bf16 in/out, no LDS.
__global__ __launch_bounds__(256) void ln_k(const u16* __restrict__ y,
    const float* __restrict__ g, const float* __restrict__ b, u16* __restrict__ xb) {
  int tid = threadIdx.x;
  int w = tid >> 6, lane = tid & 63;
  long row = (long)blockIdx.x * 4 + w;
  int c = lane * 8;
  long o = row * NHID + c;
  ushort4 a0 = *(const ushort4*)&y[o];
  ushort4 a1 = *(const ushort4*)&y[o + 4];
  float v[8] = {bf2f(a0.x), bf2f(a0.y), bf2f(a0.z), bf2f(a0.w),
                bf2f(a1.x), bf2f(a1.y), bf2f(a1.z), bf2f(a1.w)};
  float s = 0.f, sq = 0.f;
  #pragma unroll
  for (int j = 0; j < 8; ++j) { s += v[j]; sq += v[j] * v[j]; }
  #pragma unroll
  for (int off = 1; off < 64; off <<= 1) {
    s += __shfl_xor(s, off);
    sq += __shfl_xor(sq, off);
  }
  float mean = s * (1.f / 512.f);
  float inv = rsqrtf(sq * (1.f / 512.f) - mean * mean + LN_EPS);
  float4 ga = *(const float4*)&g[c], gb = *(const float4*)&g[c + 4];
  float4 ba = *(const float4*)&b[c], bb = *(const float4*)&b[c + 4];
  float gg[8] = {ga.x, ga.y, ga.z, ga.w, gb.x, gb.y, gb.z, gb.w};
  float bv[8] = {ba.x, ba.y, ba.z, ba.w, bb.x, bb.y, bb.z, bb.w};
  ushort4 o0, o1;
  o0.x = f2bf((v[0] - mean) * inv * gg[0] + bv[0]);
  o0.y = f2bf((v[1] - mean) * inv * gg[1] + bv[1]);
  o0.z = f2bf((v[2] - mean) * inv * gg[2] + bv[2]);
  o0.w = f2bf((v[3] - mean) * inv * gg[3] + bv[3]);
  o1.x = f2bf((v[4] - mean) * inv * gg[4] + bv[4]);
  o1.y = f2bf((v[5] - mean) * inv * gg[5] + bv[5]);
  o1.z = f2bf((v[6] - mean) * inv * gg[6] + bv[6]);
  o1.w = f2bf((v[7] - mean) * inv * gg[7] + bv[7]);
  *(ushort4*)&xb[o] = o0;
  *(ushort4*)&xb[o + 4] = o1;
}

// ---------------------------------------------------------------------------
// Final FC weight transpose: W[16384][64] f32 -> Wt[sel*64 + n][16384] bf16.
__global__ __launch_bounds__(256) void fcT_k(const float* __restrict__ W1,
    const float* __restrict__ W2, u16* __restrict__ Wt) {
  __shared__ float t[64][65];
  int sel = blockIdx.y;
  const float* W = sel ? W2 : W1;
  int k0 = blockIdx.x * 64;
  int tx = threadIdx.x & 63, ty = threadIdx.x >> 6;
  #pragma unroll
  for (int i = 0; i < 16; ++i)
    t[ty + 4 * i][tx] = W[(long)(k0 + ty + 4 * i) * 64 + tx];
  __syncthreads();
  #pragma unroll
  for (int i = 0; i < 16; ++i)
    Wt[(long)(sel * 64 + ty + 4 * i) * 16384 + k0 + tx] = f2bf(t[tx][ty + 4 * i]);
}

// ---------------------------------------------------------------------------
// Final FC GEMM, K-split: part[ks][1024][128] = A[m][ks-chunk]*Wt[n][ks-chunk]^T
__global__ __launch_bounds__(256, 2) void gemm_fc(const u16* __restrict__ A,
    const u16* __restrict__ Bt, float* __restrict__ part) {
  __shared__ u16 As[128 * 32];
  __shared__ u16 Bs[128 * 32];
  const int tid = threadIdx.x;
  const int wave = tid >> 6, lane = tid & 63;
  const int ks = blockIdx.x;
  const long m0 = (long)blockIdx.y * 128;
  const int kbase = ks * 512;
  const int wr = wave >> 1, wc = wave & 1;
  const int srow = lane >> 2;
  const int sg = (lane & 3) ^ ((srow >> 1) & 3);
  const int fr = lane & 15;
  const int kq = lane >> 4;
  f32x4 acc[4][4] = {};
  const int kqx = (kq ^ ((fr >> 1) & 3)) * 8;
  for (int k0 = 0; k0 < 512; k0 += 32) {
    #pragma unroll
    for (int i = 0; i < 2; ++i) {
      int c = 2 * wave + i;
      gload16(A + (m0 + 16 * c + srow) * 16384L + kbase + k0 + sg * 8, &As[c * 512]);
      gload16(Bt + (long)(16 * c + srow) * 16384L + kbase + k0 + sg * 8, &Bs[c * 512]);
    }
    __syncthreads();
    bf16x8 af[4], bfv[4];
    #pragma unroll
    for (int mi = 0; mi < 4; ++mi)
      af[mi] = *(const bf16x8*)&As[(wr * 64 + mi * 16 + fr) * 32 + kqx];
    #pragma unroll
    for (int ni = 0; ni < 4; ++ni)
      bfv[ni] = *(const bf16x8*)&Bs[(wc * 64 + ni * 16 + fr) * 32 + kqx];
    #pragma unroll
    for (int mi = 0; mi < 4; ++mi)
      #pragma unroll
      for (int ni = 0; ni < 4; ++ni)
        acc[mi][ni] = __builtin_amdgcn_mfma_f32_16x16x32_bf16(af[mi], bfv[ni], acc[mi][ni], 0, 0, 0);
    __syncthreads();
  }
  #pragma unroll
  for (int ni = 0; ni < 4; ++ni) {
    int n = wc * 64 + ni * 16 + fr;
    #pragma unroll
    for (int mi = 0; mi < 4; ++mi) {
      long rr = m0 + wr * 64 + mi * 16 + kq * 4;
      #pragma unroll
      for (int j = 0; j < 4; ++j)
        part[((long)ks * 1024 + rr + j) * 128 + n] = acc[mi][ni][j];
    }
  }
}

__global__ __launch_bounds__(256) void fc_red_k(const float* __restrict__ part,
    const float* __restrict__ bfc1, const float* __restrict__ bfc2,
    float* __restrict__ out) {
  int idx = blockIdx.x * 256 + threadIdx.x;
  int sel = idx >> 16;
  int rem = idx & 65535;
  int b = rem >> 6, z = rem & 63;
  float v = sel ? bfc2[z] : bfc1[z];
  #pragma unroll
  for (int ks = 0; ks < 32; ++ks)
    v += part[((long)ks * 1024 + b) * 128 + sel * 64 + z];
  out[idx] = v;
}

// ---------------------------------------------------------------------------
extern "C" void kernel_launch(void* const* d_in, const int* in_sizes, int n_in,
                              void* d_out, int out_size, void* d_ws, size_t ws_size,
                              hipStream_t stream) {
  const int* node_types = (const int*)d_in[0];
  const int* adj_bits = (const int*)d_in[1];
  const float* Wpos = (const float*)d_in[2];
  const float* bpos = (const float*)d_in[3];
  const float* Wnode = (const float*)d_in[4];
  const float* bnode = (const float*)d_in[5];
  const float* eWq = (const float*)d_in[6];
  const float* eWk = (const float*)d_in[7];
  const float* eWv = (const float*)d_in[8];
  const float* eWo = (const float*)d_in[9];
  const float* eW1 = (const float*)d_in[10];
  const float* eW2 = (const float*)d_in[11];
  const float* ebq = (const float*)d_in[12];
  const float* ebk = (const float*)d_in[13];
  const float* ebv = (const float*)d_in[14];
  const float* ebo = (const float*)d_in[15];
  const float* eb1 = (const float*)d_in[16];
  const float* eb2 = (const float*)d_in[17];
  const float* ln1g = (const float*)d_in[18];
  const float* ln1b = (const float*)d_in[19];
  const float* ln2g = (const float*)d_in[20];
  const float* ln2b = (const float*)d_in[21];
  const float* Wfc1 = (const float*)d_in[22];
  const float* bfc1 = (const float*)d_in[23];
  const float* Wfc2 = (const float*)d_in[24];
  const float* bfc2 = (const float*)d_in[25];

  char* ws = (char*)d_ws;
  size_t off = 0;
  auto carve = [&](size_t bytes) {
    void* p = ws + off;
    off += (bytes + 255) & ~(size_t)255;
    return p;
  };
  u16* Wqkv_t = (u16*)carve((size_t)NLAY * 1536 * 512 * 2);
  u16* Wo_t = (u16*)carve((size_t)NLAY * 512 * 512 * 2);
  u16* W1_t = (u16*)carve((size_t)NLAY * 512 * 512 * 2);
  u16* W2_t = (u16*)carve((size_t)NLAY * 512 * 512 * 2);
  u16* xb = (u16*)carve((size_t)MTOT * NHID * 2);       // 32 MB: layer state
  u16* qk = (u16*)carve((size_t)MTOT * 1024 * 2);       // 64 MB: Q,K / ybuf / Wt_fc
  u16* vt = (u16*)carve((size_t)MTOT * NHID * 2);       // 32 MB: V transposed
  u16* obuf = (u16*)carve((size_t)MTOT * NHID * 2);     // 32 MB: attn out / hbuf / part
  u32* maskb = (u32*)carve((size_t)NB * MAXN * 4);
  u16* ybuf = qk;                 // pre-LN y (qk dead after attn)
  u16* hbuf = obuf;               // MLP hidden
  u16* Wt_fc = qk;                // FC-time alias: 4 MB
  float* part_fc = (float*)obuf;  // FC-time alias: 16.8 MB

  // --- prep ---
  mask_k<<<NB / 8, 256, 0, stream>>>(adj_bits, maskb);
  embed_k<<<(MTOT * 128) / 256, 256, 0, stream>>>(node_types, Wpos, bpos, Wnode, bnode, xb);
  dim3 tg(16, 16, NLAY);
  tconv_k<<<tg, 256, 0, stream>>>(eWq, Wqkv_t, 0, 1536);
  tconv_k<<<tg, 256, 0, stream>>>(eWk, Wqkv_t, 512, 1536);
  tconv_k<<<tg, 256, 0, stream>>>(eWv, Wqkv_t, 1024, 1536);
  tconv_k<<<tg, 256, 0, stream>>>(eWo, Wo_t, 0, 512);
  tconv_k<<<tg, 256, 0, stream>>>(eW1, W1_t, 0, 512);
  tconv_k<<<tg, 256, 0, stream>>>(eW2, W2_t, 0, 512);

  // --- encoder layers ---
  for (int l = 0; l < NLAY; ++l) {
    size_t lw = (size_t)l * 512 * 512;
    gemm_qkv<<<dim3(12, MTOT / 128), 256, 0, stream>>>(
        xb, Wqkv_t + (size_t)l * 1536 * 512,
        ebq + l * 512, ebk + l * 512, ebv + l * 512, qk, vt);
    attn_k<<<NB * NHEAD / 4, 256, 0, stream>>>(qk, vt, maskb, obuf);
    gemm_bt<3><<<dim3(4, MTOT / 128), 256, 0, stream>>>(
        obuf, Wo_t + lw, ebo + l * 512, xb, ybuf, 512, 512);
    ln_k<<<MTOT / 4, 256, 0, stream>>>(ybuf, ln1g + l * 512, ln1b + l * 512, xb);
    gemm_bt<2><<<dim3(4, MTOT / 128), 256, 0, stream>>>(
        xb, W1_t + lw, eb1 + l * 512, nullptr, hbuf, 512, 512);
    gemm_bt<3><<<dim3(4, MTOT / 128), 256, 0, stream>>>(
        hbuf, W2_t + lw, eb2 + l * 512, xb, ybuf, 512, 512);
    ln_k<<<MTOT / 4, 256, 0, stream>>>(ybuf, ln2g + l * 512, ln2b + l * 512, xb);
  }

  // --- final FC: transpose weights (dead qk region), K-split MFMA, reduce ---
  fcT_k<<<dim3(256, 2), 256, 0, stream>>>(Wfc1, Wfc2, Wt_fc);
  gemm_fc<<<dim3(32, 8), 256, 0, stream>>>(xb, Wt_fc, part_fc);
  fc_red_k<<<512, 256, 0, stream>>>(part_fc, bfc1, bfc2, (float*)d_out);
}

// Round 6
// 1497.049 us; speedup vs baseline: 1.2823x; 1.0986x over previous
//
#include <hip/hip_runtime.h>

// PACE DAG-transformer encoder, MI355X bf16-MFMA implementation. Round 6:
// A/B experiment: gemm_qkv<SWZ> (layers 0,2,4 swizzled LDS, layers 1,3,5
// r2-exact linear LDS), vt scatter epilogue REMOVED (V packed [row][512],
// attention does per-wave LDS transpose of its 32x64 V tile). Attention
// barriers removed (per-wave-private LDS only needs in-wave lgkmcnt order).

typedef unsigned short u16;
typedef unsigned int u32;
typedef __attribute__((ext_vector_type(8))) short bf16x8;
typedef __attribute__((ext_vector_type(4))) float f32x4;

#define NB 1024
#define MAXN 32
#define NHID 512
#define NHEAD 8
#define NLAY 6
#define MTOT (NB * MAXN)   // 32768 rows
#define ATT_SCALE 0.125f
#define LN_EPS 1e-5f

__device__ __forceinline__ float bf2f(u16 h) { return __uint_as_float(((u32)h) << 16); }
__device__ __forceinline__ u16 f2bf(float f) {
  u32 u = __float_as_uint(f);
  return (u16)((u + 0x7fffu + ((u >> 16) & 1u)) >> 16);
}

__device__ __forceinline__ void gload16(const void* g, void* l) {
  __builtin_amdgcn_global_load_lds((const __attribute__((address_space(1))) void*)g,
                                   (__attribute__((address_space(3))) void*)l, 16, 0, 0);
}

// XCD-aware remap: all NX n-blocks of one m-panel on one XCD (FETCH 138->36MB, r5).
__device__ __forceinline__ void xcd_remap(int l, int NX, int& mt, int& nt) {
  int xcd = l & 7;
  int s = l >> 3;
  int mg = s / NX;
  nt = s - mg * NX;
  mt = mg * 8 + xcd;
}

// ---------------------------------------------------------------------------
// DAG reachability mask: per (b,q) a 32-bit "allowed key" mask.
__global__ __launch_bounds__(256) void mask_k(const int* __restrict__ adj, u32* __restrict__ mask) {
  __shared__ u32 r[8][32];
  int tid = threadIdx.x;
  int g = tid >> 5, i = tid & 31;
  int b = blockIdx.x * 8 + g;
  const int* ab = adj + ((long)b * 32 + i) * 32;
  u32 m = 0;
  for (int j = i + 1; j < 32; ++j)
    if (ab[j]) m |= (1u << j);
  r[g][i] = m;
  __syncthreads();
  for (int it = 0; it < 5; ++it) {
    u32 cur = r[g][i];
    u32 acc = cur;
    #pragma unroll
    for (int j = 0; j < 32; ++j)
      if ((cur >> j) & 1u) acc |= r[g][j];
    __syncthreads();
    r[g][i] = acc;
    __syncthreads();
  }
  u32 am = 1u << i;
  #pragma unroll
  for (int k = 0; k < 32; ++k) am |= ((r[g][k] >> i) & 1u) << k;
  mask[b * 32 + i] = am;
}

// ---------------------------------------------------------------------------
// Embedding -> xb (bf16 only).
__global__ __launch_bounds__(256) void embed_k(const int* __restrict__ types,
    const float* __restrict__ Wpos, const float* __restrict__ bpos,
    const float* __restrict__ Wnode, const float* __restrict__ bnode,
    u16* __restrict__ xb) {
  int i = blockIdx.x * 256 + threadIdx.x;
  int row = i >> 7, c = (i & 127) * 4;
  int b = row >> 5, n = row & 31;
  float v[4];
  if (c < 256) {
    int tp = types[b * 32 + n];
    const float* w = &Wnode[tp * 256 + c];
    #pragma unroll
    for (int j = 0; j < 4; ++j) v[j] = fmaxf(w[j] + bnode[c + j], 0.f);
  } else {
    int cc = c - 256;
    const float* w = &Wpos[n * 256 + cc];
    #pragma unroll
    for (int j = 0; j < 4; ++j) v[j] = w[j] + bpos[cc + j];
  }
  ushort4 h; h.x = f2bf(v[0]); h.y = f2bf(v[1]); h.z = f2bf(v[2]); h.w = f2bf(v[3]);
  *(ushort4*)&xb[(long)row * NHID + c] = h;
}

// ---------------------------------------------------------------------------
// Weight transpose + f32->bf16: W[l][k][n] -> Wt[l][n_off+n][k]
__global__ __launch_bounds__(256) void tconv_k(const float* __restrict__ W,
    u16* __restrict__ Wt, int n_off, int n_total) {
  __shared__ float tile[32][33];
  int l = blockIdx.z;
  int k0 = blockIdx.x * 32, n0 = blockIdx.y * 32;
  int tx = threadIdx.x & 31, ty = threadIdx.x >> 5;
  const float* src = W + (size_t)l * NHID * NHID;
  #pragma unroll
  for (int i = 0; i < 4; ++i)
    tile[ty + 8 * i][tx] = src[(size_t)(k0 + ty + 8 * i) * NHID + n0 + tx];
  __syncthreads();
  u16* dst = Wt + (size_t)l * n_total * NHID;
  #pragma unroll
  for (int i = 0; i < 4; ++i)
    dst[(size_t)(n_off + n0 + ty + 8 * i) * NHID + k0 + tx] = f2bf(tile[tx][ty + 8 * i]);
}

// ---------------------------------------------------------------------------
// bf16 MFMA GEMM (N=512 class): C = A*Bt^T + bias [+res] [relu].
// 128x128 tile, BK=32, single-buffer LDS, swizzle, XCD remap.
// EPI: 1 = bias; 2 = bias+relu; 3 = bias+residual(bf16)
template <int EPI>
__global__ __launch_bounds__(256, 2) void gemm_bt(
    const u16* __restrict__ A, const u16* __restrict__ Bt,
    const float* __restrict__ bias0, const u16* __restrict__ res,
    u16* __restrict__ Cout, int N, int K) {
  __shared__ u16 As[128 * 32];
  __shared__ u16 Bs[128 * 32];
  const int tid = threadIdx.x;
  const int wave = tid >> 6, lane = tid & 63;
  int mt, nt;
  xcd_remap(blockIdx.x + gridDim.x * blockIdx.y, gridDim.x, mt, nt);
  const long m0 = (long)mt * 128;
  const int n0 = nt * 128;
  const int wr = wave >> 1, wc = wave & 1;
  const int srow = lane >> 2;
  const int sg = (lane & 3) ^ ((srow >> 1) & 3);
  const int fr = lane & 15;
  const int kq = lane >> 4;
  f32x4 acc[4][4] = {};

  const int kqx = (kq ^ ((fr >> 1) & 3)) * 8;
  for (int k0 = 0; k0 < K; k0 += 32) {
    #pragma unroll
    for (int i = 0; i < 2; ++i) {
      int c = 2 * wave + i;
      gload16(A + (m0 + 16 * c + srow) * (long)K + k0 + sg * 8, &As[c * 512]);
      gload16(Bt + (long)(n0 + 16 * c + srow) * K + k0 + sg * 8, &Bs[c * 512]);
    }
    __syncthreads();
    bf16x8 af[4], bfv[4];
    #pragma unroll
    for (int mi = 0; mi < 4; ++mi)
      af[mi] = *(const bf16x8*)&As[(wr * 64 + mi * 16 + fr) * 32 + kqx];
    #pragma unroll
    for (int ni = 0; ni < 4; ++ni)
      bfv[ni] = *(const bf16x8*)&Bs[(wc * 64 + ni * 16 + fr) * 32 + kqx];
    #pragma unroll
    for (int mi = 0; mi < 4; ++mi)
      #pragma unroll
      for (int ni = 0; ni < 4; ++ni)
        acc[mi][ni] = __builtin_amdgcn_mfma_f32_16x16x32_bf16(af[mi], bfv[ni], acc[mi][ni], 0, 0, 0);
    __syncthreads();
  }

  #pragma unroll
  for (int ni = 0; ni < 4; ++ni) {
    int n = n0 + wc * 64 + ni * 16 + fr;
    float bias = bias0[n];
    #pragma unroll
    for (int mi = 0; mi < 4; ++mi) {
      long r = m0 + wr * 64 + mi * 16 + kq * 4;
      #pragma unroll
      for (int j = 0; j < 4; ++j) {
        float v = acc[mi][ni][j] + bias;
        if (EPI == 2) v = fmaxf(v, 0.f);
        if (EPI == 3) v += bf2f(res[(r + j) * (long)N + n]);
        Cout[(r + j) * (long)N + n] = f2bf(v);
      }
    }
  }
}

// ---------------------------------------------------------------------------
// QKV GEMM A/B variant: A[32768][512] * Wqkv_t[1536][512]^T.
// Q,K -> qk[row][1024]; V -> v[row][512] (both plain packed stores, r2-style).
// SWZ=1: conflict-free LDS granule swizzle; SWZ=0: r2-exact linear.
template <int SWZ>
__global__ __launch_bounds__(256, 2) void gemm_qkv(
    const u16* __restrict__ A, const u16* __restrict__ Bt,
    const float* __restrict__ bq, const float* __restrict__ bk,
    const float* __restrict__ bv, u16* __restrict__ qk, u16* __restrict__ v) {
  __shared__ u16 As[128 * 32];
  __shared__ u16 Bs[128 * 32];
  const int tid = threadIdx.x;
  const int wave = tid >> 6, lane = tid & 63;
  int mt, nt;
  xcd_remap(blockIdx.x + gridDim.x * blockIdx.y, gridDim.x, mt, nt);
  const long m0 = (long)mt * 128;
  const int n0 = nt * 128;
  const int wr = wave >> 1, wc = wave & 1;
  const int srow = lane >> 2;
  const int sg = SWZ ? ((lane & 3) ^ ((srow >> 1) & 3)) : (lane & 3);
  const int fr = lane & 15;
  const int kq = lane >> 4;
  f32x4 acc[4][4] = {};

  const int kqx = SWZ ? ((kq ^ ((fr >> 1) & 3)) * 8) : (kq * 8);
  for (int k0 = 0; k0 < 512; k0 += 32) {
    #pragma unroll
    for (int i = 0; i < 2; ++i) {
      int c = 2 * wave + i;
      gload16(A + (m0 + 16 * c + srow) * 512L + k0 + sg * 8, &As[c * 512]);
      gload16(Bt + (long)(n0 + 16 * c + srow) * 512 + k0 + sg * 8, &Bs[c * 512]);
    }
    __syncthreads();
    bf16x8 af[4], bfv[4];
    #pragma unroll
    for (int mi = 0; mi < 4; ++mi)
      af[mi] = *(const bf16x8*)&As[(wr * 64 + mi * 16 + fr) * 32 + kqx];
    #pragma unroll
    for (int ni = 0; ni < 4; ++ni)
      bfv[ni] = *(const bf16x8*)&Bs[(wc * 64 + ni * 16 + fr) * 32 + kqx];
    #pragma unroll
    for (int mi = 0; mi < 4; ++mi)
      #pragma unroll
      for (int ni = 0; ni < 4; ++ni)
        acc[mi][ni] = __builtin_amdgcn_mfma_f32_16x16x32_bf16(af[mi], bfv[ni], acc[mi][ni], 0, 0, 0);
    __syncthreads();
  }

  #pragma unroll
  for (int ni = 0; ni < 4; ++ni) {
    int n = n0 + wc * 64 + ni * 16 + fr;
    float bias = (n < 512) ? bq[n] : ((n < 1024) ? bk[n - 512] : bv[n - 1024]);
    #pragma unroll
    for (int mi = 0; mi < 4; ++mi) {
      long r = m0 + wr * 64 + mi * 16 + kq * 4;
      #pragma unroll
      for (int j = 0; j < 4; ++j) {
        u16 hv = f2bf(acc[mi][ni][j] + bias);
        long rr = r + j;
        if (n < 1024) qk[rr * 1024 + n] = hv;
        else          v[rr * 512 + (n - 1024)] = hv;
      }
    }
  }
}

// ---------------------------------------------------------------------------
// MFMA attention: 1 wave per (b,head), 4 waves/block, no barriers.
// V read packed [row][512], transposed through per-wave LDS tile [64 d][32 n].
__global__ __launch_bounds__(256) void attn_k(const u16* __restrict__ qk,
    const u16* __restrict__ vfull, const u32* __restrict__ mask, u16* __restrict__ o) {
  __shared__ u16 vs_[4][64][40];     // [d][node], stride 40 u16 = 80 B (16B-aligned)
  __shared__ u16 p_lds[4][32][40];
  int tid = threadIdx.x;
  int w = tid >> 6, lane = tid & 63;
  int idx = blockIdx.x * 4 + w;
  int b = idx >> 3, h = idx & 7;
  const u16* qbase = qk + (long)b * 32 * 1024 + h * 64;
  const u16* kbase = qbase + 512;
  int g = lane >> 4, r = lane & 15;

  // --- issue V loads early (lane -> node = lane>>1, d-half = lane&1) ---
  int node = lane >> 1, dh = lane & 1;
  const u16* vsrc = vfull + ((long)b * 32 + node) * 512 + h * 64 + dh * 32;
  bf16x8 vr[4];
  #pragma unroll
  for (int i = 0; i < 4; ++i) vr[i] = *(const bf16x8*)(vsrc + i * 8);

  // --- S^T = K · Q^T ---
  f32x4 s[2][2] = {};
  #pragma unroll
  for (int ks = 0; ks < 2; ++ks) {
    bf16x8 kf[2], qf[2];
    #pragma unroll
    for (int mi = 0; mi < 2; ++mi)
      kf[mi] = *(const bf16x8*)(kbase + (long)(mi * 16 + r) * 1024 + ks * 32 + g * 8);
    #pragma unroll
    for (int nj = 0; nj < 2; ++nj)
      qf[nj] = *(const bf16x8*)(qbase + (long)(nj * 16 + r) * 1024 + ks * 32 + g * 8);
    #pragma unroll
    for (int mi = 0; mi < 2; ++mi)
      #pragma unroll
      for (int nj = 0; nj < 2; ++nj)
        s[mi][nj] = __builtin_amdgcn_mfma_f32_16x16x32_bf16(kf[mi], qf[nj], s[mi][nj], 0, 0, 0);
  }

  // --- stash V transposed into per-wave LDS ---
  #pragma unroll
  for (int i = 0; i < 4; ++i)
    #pragma unroll
    for (int t = 0; t < 8; ++t)
      vs_[w][dh * 32 + i * 8 + t][node] = (u16)vr[i][t];

  // --- masked softmax per query column ---
  #pragma unroll
  for (int nj = 0; nj < 2; ++nj) {
    int q = nj * 16 + r;
    u32 mk = mask[b * 32 + q];
    float vv[8];
    float mx = -1e30f;
    #pragma unroll
    for (int mi = 0; mi < 2; ++mi)
      #pragma unroll
      for (int j = 0; j < 4; ++j) {
        int k = mi * 16 + g * 4 + j;
        float val = ((mk >> k) & 1u) ? s[mi][nj][j] * ATT_SCALE : -1e30f;
        vv[mi * 4 + j] = val;
        mx = fmaxf(mx, val);
      }
    mx = fmaxf(mx, __shfl_xor(mx, 16));
    mx = fmaxf(mx, __shfl_xor(mx, 32));
    float sum = 0.f;
    #pragma unroll
    for (int i = 0; i < 8; ++i) { vv[i] = __expf(vv[i] - mx); sum += vv[i]; }
    sum += __shfl_xor(sum, 16);
    sum += __shfl_xor(sum, 32);
    float inv = 1.f / sum;
    #pragma unroll
    for (int mi = 0; mi < 2; ++mi) {
      ushort4 pk;
      pk.x = f2bf(vv[mi * 4 + 0] * inv);
      pk.y = f2bf(vv[mi * 4 + 1] * inv);
      pk.z = f2bf(vv[mi * 4 + 2] * inv);
      pk.w = f2bf(vv[mi * 4 + 3] * inv);
      *(ushort4*)&p_lds[w][q][mi * 16 + g * 4] = pk;
    }
  }
  // no barrier: p_lds[w]/vs_[w] are wave-private; lgkmcnt orders in-wave.

  // --- O = P · V: B-frag vf[t] = V[node=g*8+t][d=nd*16+r] = vs_[d][g*8+t] ---
  bf16x8 pa[2];
  #pragma unroll
  for (int mi = 0; mi < 2; ++mi)
    pa[mi] = *(const bf16x8*)&p_lds[w][mi * 16 + r][g * 8];
  f32x4 oacc[2][4] = {};
  #pragma unroll
  for (int nd = 0; nd < 4; ++nd) {
    bf16x8 vf = *(const bf16x8*)&vs_[w][nd * 16 + r][g * 8];
    #pragma unroll
    for (int mi = 0; mi < 2; ++mi)
      oacc[mi][nd] = __builtin_amdgcn_mfma_f32_16x16x32_bf16(pa[mi], vf, oacc[mi][nd], 0, 0, 0);
  }
  #pragma unroll
  for (int mi = 0; mi < 2; ++mi)
    #pragma unroll
    for (int j = 0; j < 4; ++j) {
      int q = mi * 16 + g * 4 + j;
      u16* og = o + ((long)b * 32 + q) * NHID + h * 64;
      #pragma unroll
      for (int nd = 0; nd < 4; ++nd)
        og[nd * 16 + r] = f2bf(oacc[mi][nd][j]);
    }
}

// ---------------------------------------------------------------------------
// LayerNorm: xb = LN(y)*g + b. 1 wave per 512-col row, bf16 in/out, no LDS.
__global__ __launch_bounds__(256) void ln_k(const u16* __restrict__ y,
    const float* __restrict__ g, const float* __restrict__ b, u16* __restrict__ xb) {
  int tid = threadIdx.x;
  int w = tid >> 6, lane = tid & 63;
  long row = (long)blockIdx.x * 4 + w;
  int c = lane * 8;
  long o = row * NHID + c;
  ushort4 a0 = *(const ushort4*)&y[o];
  ushort4 a1 = *(const ushort4*)&y[o + 4];
  float v[8] = {bf2f(a0.x), bf2f(a0.y), bf2f(a0.z), bf2f(a0.w),
                bf2f(a1.x), bf2f(a1.y), bf2f(a1.z), bf2f(a1.w)};
  float s = 0.f, sq = 0.f;
  #pragma unroll
  for (int j = 0; j < 8; ++j) { s += v[j]; sq += v[j] * v[j]; }
  #pragma unroll
  for (int off = 1; off < 64; off <<= 1) {
    s += __shfl_xor(s, off);
    sq += __shfl_xor(sq, off);
  }
  float mean = s * (1.f / 512.f);
  float inv = rsqrtf(sq * (1.f / 512.f) - mean * mean + LN_EPS);
  float4 ga = *(const float4*)&g[c], gb = *(const float4*)&g[c + 4];
  float4 ba = *(const float4*)&b[c], bb = *(const float4*)&b[c + 4];
  float gg[8] = {ga.x, ga.y, ga.z, ga.w, gb.x, gb.y, gb.z, gb.w};
  float bv[8] = {ba.x, ba.y, ba.z, ba.w, bb.x, bb.y, bb.z, bb.w};
  ushort4 o0, o1;
  o0.x = f2bf((v[0] - mean) * inv * gg[0] + bv[0]);
  o0.y = f2bf((v[1] - mean) * inv * gg[1] + bv[1]);
  o0.z = f2bf((v[2] - mean) * inv * gg[2] + bv[2]);
  o0.w = f2bf((v[3] - mean) * inv * gg[3] + bv[3]);
  o1.x = f2bf((v[4] - mean) * inv * gg[4] + bv[4]);
  o1.y = f2bf((v[5] - mean) * inv * gg[5] + bv[5]);
  o1.z = f2bf((v[6] - mean) * inv * gg[6] + bv[6]);
  o1.w = f2bf((v[7] - mean) * inv * gg[7] + bv[7]);
  *(ushort4*)&xb[o] = o0;
  *(ushort4*)&xb[o + 4] = o1;
}

// ---------------------------------------------------------------------------
// Final FC weight transpose: W[16384][64] f32 -> Wt[sel*64 + n][16384] bf16.
__global__ __launch_bounds__(256) void fcT_k(const float* __restrict__ W1,
    const float* __restrict__ W2, u16* __restrict__ Wt) {
  __shared__ float t[64][65];
  int sel = blockIdx.y;
  const float* W = sel ? W2 : W1;
  int k0 = blockIdx.x * 64;
  int tx = threadIdx.x & 63, ty = threadIdx.x >> 6;
  #pragma unroll
  for (int i = 0; i < 16; ++i)
    t[ty + 4 * i][tx] = W[(long)(k0 + ty + 4 * i) * 64 + tx];
  __syncthreads();
  #pragma unroll
  for (int i = 0; i < 16; ++i)
    Wt[(long)(sel * 64 + ty + 4 * i) * 16384 + k0 + tx] = f2bf(t[tx][ty + 4 * i]);
}

// ---------------------------------------------------------------------------
// Final FC GEMM, K-split: part[ks][1024][128] = A[m][ks-chunk]*Wt[n][ks-chunk]^T
__global__ __launch_bounds__(256, 2) void gemm_fc(const u16* __restrict__ A,
    const u16* __restrict__ Bt, float* __restrict__ part) {
  __shared__ u16 As[128 * 32];
  __shared__ u16 Bs[128 * 32];
  const int tid = threadIdx.x;
  const int wave = tid >> 6, lane = tid & 63;
  const int ks = blockIdx.x;
  const long m0 = (long)blockIdx.y * 128;
  const int kbase = ks * 512;
  const int wr = wave >> 1, wc = wave & 1;
  const int srow = lane >> 2;
  const int sg = (lane & 3) ^ ((srow >> 1) & 3);
  const int fr = lane & 15;
  const int kq = lane >> 4;
  f32x4 acc[4][4] = {};
  const int kqx = (kq ^ ((fr >> 1) & 3)) * 8;
  for (int k0 = 0; k0 < 512; k0 += 32) {
    #pragma unroll
    for (int i = 0; i < 2; ++i) {
      int c = 2 * wave + i;
      gload16(A + (m0 + 16 * c + srow) * 16384L + kbase + k0 + sg * 8, &As[c * 512]);
      gload16(Bt + (long)(16 * c + srow) * 16384L + kbase + k0 + sg * 8, &Bs[c * 512]);
    }
    __syncthreads();
    bf16x8 af[4], bfv[4];
    #pragma unroll
    for (int mi = 0; mi < 4; ++mi)
      af[mi] = *(const bf16x8*)&As[(wr * 64 + mi * 16 + fr) * 32 + kqx];
    #pragma unroll
    for (int ni = 0; ni < 4; ++ni)
      bfv[ni] = *(const bf16x8*)&Bs[(wc * 64 + ni * 16 + fr) * 32 + kqx];
    #pragma unroll
    for (int mi = 0; mi < 4; ++mi)
      #pragma unroll
      for (int ni = 0; ni < 4; ++ni)
        acc[mi][ni] = __builtin_amdgcn_mfma_f32_16x16x32_bf16(af[mi], bfv[ni], acc[mi][ni], 0, 0, 0);
    __syncthreads();
  }
  #pragma unroll
  for (int ni = 0; ni < 4; ++ni) {
    int n = wc * 64 + ni * 16 + fr;
    #pragma unroll
    for (int mi = 0; mi < 4; ++mi) {
      long rr = m0 + wr * 64 + mi * 16 + kq * 4;
      #pragma unroll
      for (int j = 0; j < 4; ++j)
        part[((long)ks * 1024 + rr + j) * 128 + n] = acc[mi][ni][j];
    }
  }
}

__global__ __launch_bounds__(256) void fc_red_k(const float* __restrict__ part,
    const float* __restrict__ bfc1, const float* __restrict__ bfc2,
    float* __restrict__ out) {
  int idx = blockIdx.x * 256 + threadIdx.x;
  int sel = idx >> 16;
  int rem = idx & 65535;
  int b = rem >> 6, z = rem & 63;
  float v = sel ? bfc2[z] : bfc1[z];
  #pragma unroll
  for (int ks = 0; ks < 32; ++ks)
    v += part[((long)ks * 1024 + b) * 128 + sel * 64 + z];
  out[idx] = v;
}

// ---------------------------------------------------------------------------
extern "C" void kernel_launch(void* const* d_in, const int* in_sizes, int n_in,
                              void* d_out, int out_size, void* d_ws, size_t ws_size,
                              hipStream_t stream) {
  const int* node_types = (const int*)d_in[0];
  const int* adj_bits = (const int*)d_in[1];
  const float* Wpos = (const float*)d_in[2];
  const float* bpos = (const float*)d_in[3];
  const float* Wnode = (const float*)d_in[4];
  const float* bnode = (const float*)d_in[5];
  const float* eWq = (const float*)d_in[6];
  const float* eWk = (const float*)d_in[7];
  const float* eWv = (const float*)d_in[8];
  const float* eWo = (const float*)d_in[9];
  const float* eW1 = (const float*)d_in[10];
  const float* eW2 = (const float*)d_in[11];
  const float* ebq = (const float*)d_in[12];
  const float* ebk = (const float*)d_in[13];
  const float* ebv = (const float*)d_in[14];
  const float* ebo = (const float*)d_in[15];
  const float* eb1 = (const float*)d_in[16];
  const float* eb2 = (const float*)d_in[17];
  const float* ln1g = (const float*)d_in[18];
  const float* ln1b = (const float*)d_in[19];
  const float* ln2g = (const float*)d_in[20];
  const float* ln2b = (const float*)d_in[21];
  const float* Wfc1 = (const float*)d_in[22];
  const float* bfc1 = (const float*)d_in[23];
  const float* Wfc2 = (const float*)d_in[24];
  const float* bfc2 = (const float*)d_in[25];

  char* ws = (char*)d_ws;
  size_t off = 0;
  auto carve = [&](size_t bytes) {
    void* p = ws + off;
    off += (bytes + 255) & ~(size_t)255;
    return p;
  };
  u16* Wqkv_t = (u16*)carve((size_t)NLAY * 1536 * 512 * 2);
  u16* Wo_t = (u16*)carve((size_t)NLAY * 512 * 512 * 2);
  u16* W1_t = (u16*)carve((size_t)NLAY * 512 * 512 * 2);
  u16* W2_t = (u16*)carve((size_t)NLAY * 512 * 512 * 2);
  u16* xb = (u16*)carve((size_t)MTOT * NHID * 2);       // 32 MB: layer state
  u16* qk = (u16*)carve((size_t)MTOT * 1024 * 2);       // 64 MB: Q,K / ybuf / Wt_fc
  u16* vbuf = (u16*)carve((size_t)MTOT * NHID * 2);     // 32 MB: V packed
  u16* obuf = (u16*)carve((size_t)MTOT * NHID * 2);     // 32 MB: attn out / hbuf / part
  u32* maskb = (u32*)carve((size_t)NB * MAXN * 4);
  u16* ybuf = qk;                 // pre-LN y (qk dead after attn)
  u16* hbuf = obuf;               // MLP hidden
  u16* Wt_fc = qk;                // FC-time alias: 4 MB
  float* part_fc = (float*)obuf;  // FC-time alias: 16.8 MB

  // --- prep ---
  mask_k<<<NB / 8, 256, 0, stream>>>(adj_bits, maskb);
  embed_k<<<(MTOT * 128) / 256, 256, 0, stream>>>(node_types, Wpos, bpos, Wnode, bnode, xb);
  dim3 tg(16, 16, NLAY);
  tconv_k<<<tg, 256, 0, stream>>>(eWq, Wqkv_t, 0, 1536);
  tconv_k<<<tg, 256, 0, stream>>>(eWk, Wqkv_t, 512, 1536);
  tconv_k<<<tg, 256, 0, stream>>>(eWv, Wqkv_t, 1024, 1536);
  tconv_k<<<tg, 256, 0, stream>>>(eWo, Wo_t, 0, 512);
  tconv_k<<<tg, 256, 0, stream>>>(eW1, W1_t, 0, 512);
  tconv_k<<<tg, 256, 0, stream>>>(eW2, W2_t, 0, 512);

  // --- encoder layers (A/B: even layers swizzled LDS, odd layers linear) ---
  for (int l = 0; l < NLAY; ++l) {
    size_t lw = (size_t)l * 512 * 512;
    if (l & 1)
      gemm_qkv<0><<<dim3(12, MTOT / 128), 256, 0, stream>>>(
          xb, Wqkv_t + (size_t)l * 1536 * 512,
          ebq + l * 512, ebk + l * 512, ebv + l * 512, qk, vbuf);
    else
      gemm_qkv<1><<<dim3(12, MTOT / 128), 256, 0, stream>>>(
          xb, Wqkv_t + (size_t)l * 1536 * 512,
          ebq + l * 512, ebk + l * 512, ebv + l * 512, qk, vbuf);
    attn_k<<<NB * NHEAD / 4, 256, 0, stream>>>(qk, vbuf, maskb, obuf);
    gemm_bt<3><<<dim3(4, MTOT / 128), 256, 0, stream>>>(
        obuf, Wo_t + lw, ebo + l * 512, xb, ybuf, 512, 512);
    ln_k<<<MTOT / 4, 256, 0, stream>>>(ybuf, ln1g + l * 512, ln1b + l * 512, xb);
    gemm_bt<2><<<dim3(4, MTOT / 128), 256, 0, stream>>>(
        xb, W1_t + lw, eb1 + l * 512, nullptr, hbuf, 512, 512);
    gemm_bt<3><<<dim3(4, MTOT / 128), 256, 0, stream>>>(
        hbuf, W2_t + lw, eb2 + l * 512, xb, ybuf, 512, 512);
    ln_k<<<MTOT / 4, 256, 0, stream>>>(ybuf, ln2g + l * 512, ln2b + l * 512, xb);
  }

  // --- final FC: transpose weights (dead qk region), K-split MFMA, reduce ---
  fcT_k<<<dim3(256, 2), 256, 0, stream>>>(Wfc1, Wfc2, Wt_fc);
  gemm_fc<<<dim3(32, 8), 256, 0, stream>>>(xb, Wt_fc, part_fc);
  fc_red_k<<<512, 256, 0, stream>>>(part_fc, bfc1, bfc2, (float*)d_out);
}

// Round 7
// 1401.652 us; speedup vs baseline: 1.3695x; 1.0681x over previous
//
#include <hip/hip_runtime.h>

// PACE DAG-transformer encoder, MI355X bf16-MFMA implementation. Round 7:
// All GEMMs use a 3-slot LDS pipeline with raw s_barrier + counted vmcnt
// (vmcnt(4) steady state, never 0) -> stage latency overlaps compute across
// K-steps. r6 A/B resolved: bank-conflict swizzle is time-neutral at the old
// 2-barrier loop (conflicts hidden behind stage stall); kept everywhere now
// that the stage stall is pipelined away.

typedef unsigned short u16;
typedef unsigned int u32;
typedef __attribute__((ext_vector_type(8))) short bf16x8;
typedef __attribute__((ext_vector_type(4))) float f32x4;

#define NB 1024
#define MAXN 32
#define NHID 512
#define NHEAD 8
#define NLAY 6
#define MTOT (NB * MAXN)   // 32768 rows
#define ATT_SCALE 0.125f
#define LN_EPS 1e-5f

__device__ __forceinline__ float bf2f(u16 h) { return __uint_as_float(((u32)h) << 16); }
__device__ __forceinline__ u16 f2bf(float f) {
  u32 u = __float_as_uint(f);
  return (u16)((u + 0x7fffu + ((u >> 16) & 1u)) >> 16);
}

__device__ __forceinline__ void gload16(const void* g, void* l) {
  __builtin_amdgcn_global_load_lds((const __attribute__((address_space(1))) void*)g,
                                   (__attribute__((address_space(3))) void*)l, 16, 0, 0);
}

// XCD-aware remap: all NX n-blocks of one m-panel on one XCD (FETCH 138->36MB, r5).
__device__ __forceinline__ void xcd_remap(int l, int NX, int& mt, int& nt) {
  int xcd = l & 7;
  int s = l >> 3;
  int mg = s / NX;
  nt = s - mg * NX;
  mt = mg * 8 + xcd;
}

// ---------------------------------------------------------------------------
// DAG reachability mask: per (b,q) a 32-bit "allowed key" mask.
__global__ __launch_bounds__(256) void mask_k(const int* __restrict__ adj, u32* __restrict__ mask) {
  __shared__ u32 r[8][32];
  int tid = threadIdx.x;
  int g = tid >> 5, i = tid & 31;
  int b = blockIdx.x * 8 + g;
  const int* ab = adj + ((long)b * 32 + i) * 32;
  u32 m = 0;
  for (int j = i + 1; j < 32; ++j)
    if (ab[j]) m |= (1u << j);
  r[g][i] = m;
  __syncthreads();
  for (int it = 0; it < 5; ++it) {
    u32 cur = r[g][i];
    u32 acc = cur;
    #pragma unroll
    for (int j = 0; j < 32; ++j)
      if ((cur >> j) & 1u) acc |= r[g][j];
    __syncthreads();
    r[g][i] = acc;
    __syncthreads();
  }
  u32 am = 1u << i;
  #pragma unroll
  for (int k = 0; k < 32; ++k) am |= ((r[g][k] >> i) & 1u) << k;
  mask[b * 32 + i] = am;
}

// ---------------------------------------------------------------------------
// Embedding -> xb (bf16 only).
__global__ __launch_bounds__(256) void embed_k(const int* __restrict__ types,
    const float* __restrict__ Wpos, const float* __restrict__ bpos,
    const float* __restrict__ Wnode, const float* __restrict__ bnode,
    u16* __restrict__ xb) {
  int i = blockIdx.x * 256 + threadIdx.x;
  int row = i >> 7, c = (i & 127) * 4;
  int b = row >> 5, n = row & 31;
  float v[4];
  if (c < 256) {
    int tp = types[b * 32 + n];
    const float* w = &Wnode[tp * 256 + c];
    #pragma unroll
    for (int j = 0; j < 4; ++j) v[j] = fmaxf(w[j] + bnode[c + j], 0.f);
  } else {
    int cc = c - 256;
    const float* w = &Wpos[n * 256 + cc];
    #pragma unroll
    for (int j = 0; j < 4; ++j) v[j] = w[j] + bpos[cc + j];
  }
  ushort4 h; h.x = f2bf(v[0]); h.y = f2bf(v[1]); h.z = f2bf(v[2]); h.w = f2bf(v[3]);
  *(ushort4*)&xb[(long)row * NHID + c] = h;
}

// ---------------------------------------------------------------------------
// Weight transpose + f32->bf16: W[l][k][n] -> Wt[l][n_off+n][k]
__global__ __launch_bounds__(256) void tconv_k(const float* __restrict__ W,
    u16* __restrict__ Wt, int n_off, int n_total) {
  __shared__ float tile[32][33];
  int l = blockIdx.z;
  int k0 = blockIdx.x * 32, n0 = blockIdx.y * 32;
  int tx = threadIdx.x & 31, ty = threadIdx.x >> 5;
  const float* src = W + (size_t)l * NHID * NHID;
  #pragma unroll
  for (int i = 0; i < 4; ++i)
    tile[ty + 8 * i][tx] = src[(size_t)(k0 + ty + 8 * i) * NHID + n0 + tx];
  __syncthreads();
  u16* dst = Wt + (size_t)l * n_total * NHID;
  #pragma unroll
  for (int i = 0; i < 4; ++i)
    dst[(size_t)(n_off + n0 + ty + 8 * i) * NHID + k0 + tx] = f2bf(tile[tx][ty + 8 * i]);
}

// ---------------------------------------------------------------------------
// Pipelined K-loop macro pieces (3 LDS slots, counted vmcnt, raw barrier).
// Each stage() = 4 gload16 per thread (2 A-chunks + 2 B-chunks).
// Schedule per iter t: wait vmcnt(4|0) -> s_barrier -> stage(t+2) -> compute(t).

// ---------------------------------------------------------------------------
// bf16 MFMA GEMM (N=512 class): C = A*Bt^T + bias [+res] [relu].
// 128x128 tile, BK=32, K=512 (nt=16). EPI: 1=bias; 2=bias+relu; 3=bias+res.
template <int EPI>
__global__ __launch_bounds__(256, 2) void gemm_bt(
    const u16* __restrict__ A, const u16* __restrict__ Bt,
    const float* __restrict__ bias0, const u16* __restrict__ res,
    u16* __restrict__ Cout, int N, int K) {
  __shared__ u16 As[3][128 * 32];
  __shared__ u16 Bs[3][128 * 32];
  const int tid = threadIdx.x;
  const int wave = tid >> 6, lane = tid & 63;
  int mt, nt_;
  xcd_remap(blockIdx.x + gridDim.x * blockIdx.y, gridDim.x, mt, nt_);
  const long m0 = (long)mt * 128;
  const int n0 = nt_ * 128;
  const int wr = wave >> 1, wc = wave & 1;
  const int srow = lane >> 2;
  const int sg = (lane & 3) ^ ((srow >> 1) & 3);
  const int fr = lane & 15;
  const int kq = lane >> 4;
  f32x4 acc[4][4] = {};

  auto stage = [&](int buf, int k0) {
    #pragma unroll
    for (int i = 0; i < 2; ++i) {
      int c = 2 * wave + i;
      gload16(A + (m0 + 16 * c + srow) * (long)K + k0 + sg * 8, &As[buf][c * 512]);
      gload16(Bt + (long)(n0 + 16 * c + srow) * K + k0 + sg * 8, &Bs[buf][c * 512]);
    }
  };
  stage(0, 0);
  stage(1, 32);
  const int nt = K >> 5;
  const int kqx = (kq ^ ((fr >> 1) & 3)) * 8;
  int cs = 0;
  #pragma unroll 1
  for (int t = 0; t < nt; ++t) {
    if (t + 1 < nt) asm volatile("s_waitcnt vmcnt(4)" ::: "memory");
    else            asm volatile("s_waitcnt vmcnt(0)" ::: "memory");
    __builtin_amdgcn_s_barrier();
    if (t + 2 < nt) {
      int nb = cs + 2; if (nb >= 3) nb -= 3;
      stage(nb, (t + 2) * 32);
    }
    const u16* Asl = As[cs];
    const u16* Bsl = Bs[cs];
    bf16x8 af[4], bfv[4];
    #pragma unroll
    for (int mi = 0; mi < 4; ++mi)
      af[mi] = *(const bf16x8*)&Asl[(wr * 64 + mi * 16 + fr) * 32 + kqx];
    #pragma unroll
    for (int ni = 0; ni < 4; ++ni)
      bfv[ni] = *(const bf16x8*)&Bsl[(wc * 64 + ni * 16 + fr) * 32 + kqx];
    #pragma unroll
    for (int mi = 0; mi < 4; ++mi)
      #pragma unroll
      for (int ni = 0; ni < 4; ++ni)
        acc[mi][ni] = __builtin_amdgcn_mfma_f32_16x16x32_bf16(af[mi], bfv[ni], acc[mi][ni], 0, 0, 0);
    if (++cs == 3) cs = 0;
  }

  #pragma unroll
  for (int ni = 0; ni < 4; ++ni) {
    int n = n0 + wc * 64 + ni * 16 + fr;
    float bias = bias0[n];
    #pragma unroll
    for (int mi = 0; mi < 4; ++mi) {
      long r = m0 + wr * 64 + mi * 16 + kq * 4;
      #pragma unroll
      for (int j = 0; j < 4; ++j) {
        float v = acc[mi][ni][j] + bias;
        if (EPI == 2) v = fmaxf(v, 0.f);
        if (EPI == 3) v += bf2f(res[(r + j) * (long)N + n]);
        Cout[(r + j) * (long)N + n] = f2bf(v);
      }
    }
  }
}

// ---------------------------------------------------------------------------
// QKV GEMM (pipelined): Q,K -> qk[row][1024]; V -> v[row][512].
__global__ __launch_bounds__(256, 2) void gemm_qkv(
    const u16* __restrict__ A, const u16* __restrict__ Bt,
    const float* __restrict__ bq, const float* __restrict__ bk,
    const float* __restrict__ bv, u16* __restrict__ qk, u16* __restrict__ v) {
  __shared__ u16 As[3][128 * 32];
  __shared__ u16 Bs[3][128 * 32];
  const int tid = threadIdx.x;
  const int wave = tid >> 6, lane = tid & 63;
  int mt, nt_;
  xcd_remap(blockIdx.x + gridDim.x * blockIdx.y, gridDim.x, mt, nt_);
  const long m0 = (long)mt * 128;
  const int n0 = nt_ * 128;
  const int wr = wave >> 1, wc = wave & 1;
  const int srow = lane >> 2;
  const int sg = (lane & 3) ^ ((srow >> 1) & 3);
  const int fr = lane & 15;
  const int kq = lane >> 4;
  f32x4 acc[4][4] = {};

  auto stage = [&](int buf, int k0) {
    #pragma unroll
    for (int i = 0; i < 2; ++i) {
      int c = 2 * wave + i;
      gload16(A + (m0 + 16 * c + srow) * 512L + k0 + sg * 8, &As[buf][c * 512]);
      gload16(Bt + (long)(n0 + 16 * c + srow) * 512 + k0 + sg * 8, &Bs[buf][c * 512]);
    }
  };
  stage(0, 0);
  stage(1, 32);
  const int kqx = (kq ^ ((fr >> 1) & 3)) * 8;
  int cs = 0;
  #pragma unroll 1
  for (int t = 0; t < 16; ++t) {
    if (t + 1 < 16) asm volatile("s_waitcnt vmcnt(4)" ::: "memory");
    else            asm volatile("s_waitcnt vmcnt(0)" ::: "memory");
    __builtin_amdgcn_s_barrier();
    if (t + 2 < 16) {
      int nb = cs + 2; if (nb >= 3) nb -= 3;
      stage(nb, (t + 2) * 32);
    }
    const u16* Asl = As[cs];
    const u16* Bsl = Bs[cs];
    bf16x8 af[4], bfv[4];
    #pragma unroll
    for (int mi = 0; mi < 4; ++mi)
      af[mi] = *(const bf16x8*)&Asl[(wr * 64 + mi * 16 + fr) * 32 + kqx];
    #pragma unroll
    for (int ni = 0; ni < 4; ++ni)
      bfv[ni] = *(const bf16x8*)&Bsl[(wc * 64 + ni * 16 + fr) * 32 + kqx];
    #pragma unroll
    for (int mi = 0; mi < 4; ++mi)
      #pragma unroll
      for (int ni = 0; ni < 4; ++ni)
        acc[mi][ni] = __builtin_amdgcn_mfma_f32_16x16x32_bf16(af[mi], bfv[ni], acc[mi][ni], 0, 0, 0);
    if (++cs == 3) cs = 0;
  }

  #pragma unroll
  for (int ni = 0; ni < 4; ++ni) {
    int n = n0 + wc * 64 + ni * 16 + fr;
    float bias = (n < 512) ? bq[n] : ((n < 1024) ? bk[n - 512] : bv[n - 1024]);
    #pragma unroll
    for (int mi = 0; mi < 4; ++mi) {
      long r = m0 + wr * 64 + mi * 16 + kq * 4;
      #pragma unroll
      for (int j = 0; j < 4; ++j) {
        u16 hv = f2bf(acc[mi][ni][j] + bias);
        long rr = r + j;
        if (n < 1024) qk[rr * 1024 + n] = hv;
        else          v[rr * 512 + (n - 1024)] = hv;
      }
    }
  }
}

// ---------------------------------------------------------------------------
// MFMA attention: 1 wave per (b,head), 4 waves/block, no barriers.
// V read packed [row][512], transposed through per-wave LDS tile [64 d][32 n].
__global__ __launch_bounds__(256) void attn_k(const u16* __restrict__ qk,
    const u16* __restrict__ vfull, const u32* __restrict__ mask, u16* __restrict__ o) {
  __shared__ u16 vs_[4][64][40];     // [d][node], stride 40 u16 = 80 B (16B-aligned)
  __shared__ u16 p_lds[4][32][40];
  int tid = threadIdx.x;
  int w = tid >> 6, lane = tid & 63;
  int idx = blockIdx.x * 4 + w;
  int b = idx >> 3, h = idx & 7;
  const u16* qbase = qk + (long)b * 32 * 1024 + h * 64;
  const u16* kbase = qbase + 512;
  int g = lane >> 4, r = lane & 15;

  // --- issue V loads early (lane -> node = lane>>1, d-half = lane&1) ---
  int node = lane >> 1, dh = lane & 1;
  const u16* vsrc = vfull + ((long)b * 32 + node) * 512 + h * 64 + dh * 32;
  bf16x8 vr[4];
  #pragma unroll
  for (int i = 0; i < 4; ++i) vr[i] = *(const bf16x8*)(vsrc + i * 8);

  // --- S^T = K · Q^T ---
  f32x4 s[2][2] = {};
  #pragma unroll
  for (int ks = 0; ks < 2; ++ks) {
    bf16x8 kf[2], qf[2];
    #pragma unroll
    for (int mi = 0; mi < 2; ++mi)
      kf[mi] = *(const bf16x8*)(kbase + (long)(mi * 16 + r) * 1024 + ks * 32 + g * 8);
    #pragma unroll
    for (int nj = 0; nj < 2; ++nj)
      qf[nj] = *(const bf16x8*)(qbase + (long)(nj * 16 + r) * 1024 + ks * 32 + g * 8);
    #pragma unroll
    for (int mi = 0; mi < 2; ++mi)
      #pragma unroll
      for (int nj = 0; nj < 2; ++nj)
        s[mi][nj] = __builtin_amdgcn_mfma_f32_16x16x32_bf16(kf[mi], qf[nj], s[mi][nj], 0, 0, 0);
  }

  // --- stash V transposed into per-wave LDS ---
  #pragma unroll
  for (int i = 0; i < 4; ++i)
    #pragma unroll
    for (int t = 0; t < 8; ++t)
      vs_[w][dh * 32 + i * 8 + t][node] = (u16)vr[i][t];

  // --- masked softmax per query column ---
  #pragma unroll
  for (int nj = 0; nj < 2; ++nj) {
    int q = nj * 16 + r;
    u32 mk = mask[b * 32 + q];
    float vv[8];
    float mx = -1e30f;
    #pragma unroll
    for (int mi = 0; mi < 2; ++mi)
      #pragma unroll
      for (int j = 0; j < 4; ++j) {
        int k = mi * 16 + g * 4 + j;
        float val = ((mk >> k) & 1u) ? s[mi][nj][j] * ATT_SCALE : -1e30f;
        vv[mi * 4 + j] = val;
        mx = fmaxf(mx, val);
      }
    mx = fmaxf(mx, __shfl_xor(mx, 16));
    mx = fmaxf(mx, __shfl_xor(mx, 32));
    float sum = 0.f;
    #pragma unroll
    for (int i = 0; i < 8; ++i) { vv[i] = __expf(vv[i] - mx); sum += vv[i]; }
    sum += __shfl_xor(sum, 16);
    sum += __shfl_xor(sum, 32);
    float inv = 1.f / sum;
    #pragma unroll
    for (int mi = 0; mi < 2; ++mi) {
      ushort4 pk;
      pk.x = f2bf(vv[mi * 4 + 0] * inv);
      pk.y = f2bf(vv[mi * 4 + 1] * inv);
      pk.z = f2bf(vv[mi * 4 + 2] * inv);
      pk.w = f2bf(vv[mi * 4 + 3] * inv);
      *(ushort4*)&p_lds[w][q][mi * 16 + g * 4] = pk;
    }
  }
  // no barrier: p_lds[w]/vs_[w] are wave-private; lgkmcnt orders in-wave.

  // --- O = P · V: B-frag vf[t] = V[node=g*8+t][d=nd*16+r] = vs_[d][g*8+t] ---
  bf16x8 pa[2];
  #pragma unroll
  for (int mi = 0; mi < 2; ++mi)
    pa[mi] = *(const bf16x8*)&p_lds[w][mi * 16 + r][g * 8];
  f32x4 oacc[2][4] = {};
  #pragma unroll
  for (int nd = 0; nd < 4; ++nd) {
    bf16x8 vf = *(const bf16x8*)&vs_[w][nd * 16 + r][g * 8];
    #pragma unroll
    for (int mi = 0; mi < 2; ++mi)
      oacc[mi][nd] = __builtin_amdgcn_mfma_f32_16x16x32_bf16(pa[mi], vf, oacc[mi][nd], 0, 0, 0);
  }
  #pragma unroll
  for (int mi = 0; mi < 2; ++mi)
    #pragma unroll
    for (int j = 0; j < 4; ++j) {
      int q = mi * 16 + g * 4 + j;
      u16* og = o + ((long)b * 32 + q) * NHID + h * 64;
      #pragma unroll
      for (int nd = 0; nd < 4; ++nd)
        og[nd * 16 + r] = f2bf(oacc[mi][nd][j]);
    }
}

// ---------------------------------------------------------------------------
// LayerNorm: xb = LN(y)*g + b. 1 wave per 512-col row, bf16 in/out, no LDS.
__global__ __launch_bounds__(256) void ln_k(const u16* __restrict__ y,
    const float* __restrict__ g, const float* __restrict__ b, u16* __restrict__ xb) {
  int tid = threadIdx.x;
  int w = tid >> 6, lane = tid & 63;
  long row = (long)blockIdx.x * 4 + w;
  int c = lane * 8;
  long o = row * NHID + c;
  ushort4 a0 = *(const ushort4*)&y[o];
  ushort4 a1 = *(const ushort4*)&y[o + 4];
  float v[8] = {bf2f(a0.x), bf2f(a0.y), bf2f(a0.z), bf2f(a0.w),
                bf2f(a1.x), bf2f(a1.y), bf2f(a1.z), bf2f(a1.w)};
  float s = 0.f, sq = 0.f;
  #pragma unroll
  for (int j = 0; j < 8; ++j) { s += v[j]; sq += v[j] * v[j]; }
  #pragma unroll
  for (int off = 1; off < 64; off <<= 1) {
    s += __shfl_xor(s, off);
    sq += __shfl_xor(sq, off);
  }
  float mean = s * (1.f / 512.f);
  float inv = rsqrtf(sq * (1.f / 512.f) - mean * mean + LN_EPS);
  float4 ga = *(const float4*)&g[c], gb = *(const float4*)&g[c + 4];
  float4 ba = *(const float4*)&b[c], bb = *(const float4*)&b[c + 4];
  float gg[8] = {ga.x, ga.y, ga.z, ga.w, gb.x, gb.y, gb.z, gb.w};
  float bv[8] = {ba.x, ba.y, ba.z, ba.w, bb.x, bb.y, bb.z, bb.w};
  ushort4 o0, o1;
  o0.x = f2bf((v[0] - mean) * inv * gg[0] + bv[0]);
  o0.y = f2bf((v[1] - mean) * inv * gg[1] + bv[1]);
  o0.z = f2bf((v[2] - mean) * inv * gg[2] + bv[2]);
  o0.w = f2bf((v[3] - mean) * inv * gg[3] + bv[3]);
  o1.x = f2bf((v[4] - mean) * inv * gg[4] + bv[4]);
  o1.y = f2bf((v[5] - mean) * inv * gg[5] + bv[5]);
  o1.z = f2bf((v[6] - mean) * inv * gg[6] + bv[6]);
  o1.w = f2bf((v[7] - mean) * inv * gg[7] + bv[7]);
  *(ushort4*)&xb[o] = o0;
  *(ushort4*)&xb[o + 4] = o1;
}

// ---------------------------------------------------------------------------
// Final FC weight transpose: W[16384][64] f32 -> Wt[sel*64 + n][16384] bf16.
__global__ __launch_bounds__(256) void fcT_k(const float* __restrict__ W1,
    const float* __restrict__ W2, u16* __restrict__ Wt) {
  __shared__ float t[64][65];
  int sel = blockIdx.y;
  const float* W = sel ? W2 : W1;
  int k0 = blockIdx.x * 64;
  int tx = threadIdx.x & 63, ty = threadIdx.x >> 6;
  #pragma unroll
  for (int i = 0; i < 16; ++i)
    t[ty + 4 * i][tx] = W[(long)(k0 + ty + 4 * i) * 64 + tx];
  __syncthreads();
  #pragma unroll
  for (int i = 0; i < 16; ++i)
    Wt[(long)(sel * 64 + ty + 4 * i) * 16384 + k0 + tx] = f2bf(t[tx][ty + 4 * i]);
}

// ---------------------------------------------------------------------------
// Final FC GEMM (pipelined), K-split: part[ks][1024][128].
__global__ __launch_bounds__(256, 2) void gemm_fc(const u16* __restrict__ A,
    const u16* __restrict__ Bt, float* __restrict__ part) {
  __shared__ u16 As[3][128 * 32];
  __shared__ u16 Bs[3][128 * 32];
  const int tid = threadIdx.x;
  const int wave = tid >> 6, lane = tid & 63;
  const int ks = blockIdx.x;
  const long m0 = (long)blockIdx.y * 128;
  const int kbase = ks * 512;
  const int wr = wave >> 1, wc = wave & 1;
  const int srow = lane >> 2;
  const int sg = (lane & 3) ^ ((srow >> 1) & 3);
  const int fr = lane & 15;
  const int kq = lane >> 4;
  f32x4 acc[4][4] = {};
  auto stage = [&](int buf, int k0) {
    #pragma unroll
    for (int i = 0; i < 2; ++i) {
      int c = 2 * wave + i;
      gload16(A + (m0 + 16 * c + srow) * 16384L + kbase + k0 + sg * 8, &As[buf][c * 512]);
      gload16(Bt + (long)(16 * c + srow) * 16384L + kbase + k0 + sg * 8, &Bs[buf][c * 512]);
    }
  };
  stage(0, 0);
  stage(1, 32);
  const int kqx = (kq ^ ((fr >> 1) & 3)) * 8;
  int cs = 0;
  #pragma unroll 1
  for (int t = 0; t < 16; ++t) {
    if (t + 1 < 16) asm volatile("s_waitcnt vmcnt(4)" ::: "memory");
    else            asm volatile("s_waitcnt vmcnt(0)" ::: "memory");
    __builtin_amdgcn_s_barrier();
    if (t + 2 < 16) {
      int nb = cs + 2; if (nb >= 3) nb -= 3;
      stage(nb, (t + 2) * 32);
    }
    const u16* Asl = As[cs];
    const u16* Bsl = Bs[cs];
    bf16x8 af[4], bfv[4];
    #pragma unroll
    for (int mi = 0; mi < 4; ++mi)
      af[mi] = *(const bf16x8*)&Asl[(wr * 64 + mi * 16 + fr) * 32 + kqx];
    #pragma unroll
    for (int ni = 0; ni < 4; ++ni)
      bfv[ni] = *(const bf16x8*)&Bsl[(wc * 64 + ni * 16 + fr) * 32 + kqx];
    #pragma unroll
    for (int mi = 0; mi < 4; ++mi)
      #pragma unroll
      for (int ni = 0; ni < 4; ++ni)
        acc[mi][ni] = __builtin_amdgcn_mfma_f32_16x16x32_bf16(af[mi], bfv[ni], acc[mi][ni], 0, 0, 0);
    if (++cs == 3) cs = 0;
  }
  #pragma unroll
  for (int ni = 0; ni < 4; ++ni) {
    int n = wc * 64 + ni * 16 + fr;
    #pragma unroll
    for (int mi = 0; mi < 4; ++mi) {
      long rr = m0 + wr * 64 + mi * 16 + kq * 4;
      #pragma unroll
      for (int j = 0; j < 4; ++j)
        part[((long)ks * 1024 + rr + j) * 128 + n] = acc[mi][ni][j];
    }
  }
}

__global__ __launch_bounds__(256) void fc_red_k(const float* __restrict__ part,
    const float* __restrict__ bfc1, const float* __restrict__ bfc2,
    float* __restrict__ out) {
  int idx = blockIdx.x * 256 + threadIdx.x;
  int sel = idx >> 16;
  int rem = idx & 65535;
  int b = rem >> 6, z = rem & 63;
  float v = sel ? bfc2[z] : bfc1[z];
  #pragma unroll
  for (int ks = 0; ks < 32; ++ks)
    v += part[((long)ks * 1024 + b) * 128 + sel * 64 + z];
  out[idx] = v;
}

// ---------------------------------------------------------------------------
extern "C" void kernel_launch(void* const* d_in, const int* in_sizes, int n_in,
                              void* d_out, int out_size, void* d_ws, size_t ws_size,
                              hipStream_t stream) {
  const int* node_types = (const int*)d_in[0];
  const int* adj_bits = (const int*)d_in[1];
  const float* Wpos = (const float*)d_in[2];
  const float* bpos = (const float*)d_in[3];
  const float* Wnode = (const float*)d_in[4];
  const float* bnode = (const float*)d_in[5];
  const float* eWq = (const float*)d_in[6];
  const float* eWk = (const float*)d_in[7];
  const float* eWv = (const float*)d_in[8];
  const float* eWo = (const float*)d_in[9];
  const float* eW1 = (const float*)d_in[10];
  const float* eW2 = (const float*)d_in[11];
  const float* ebq = (const float*)d_in[12];
  const float* ebk = (const float*)d_in[13];
  const float* ebv = (const float*)d_in[14];
  const float* ebo = (const float*)d_in[15];
  const float* eb1 = (const float*)d_in[16];
  const float* eb2 = (const float*)d_in[17];
  const float* ln1g = (const float*)d_in[18];
  const float* ln1b = (const float*)d_in[19];
  const float* ln2g = (const float*)d_in[20];
  const float* ln2b = (const float*)d_in[21];
  const float* Wfc1 = (const float*)d_in[22];
  const float* bfc1 = (const float*)d_in[23];
  const float* Wfc2 = (const float*)d_in[24];
  const float* bfc2 = (const float*)d_in[25];

  char* ws = (char*)d_ws;
  size_t off = 0;
  auto carve = [&](size_t bytes) {
    void* p = ws + off;
    off += (bytes + 255) & ~(size_t)255;
    return p;
  };
  u16* Wqkv_t = (u16*)carve((size_t)NLAY * 1536 * 512 * 2);
  u16* Wo_t = (u16*)carve((size_t)NLAY * 512 * 512 * 2);
  u16* W1_t = (u16*)carve((size_t)NLAY * 512 * 512 * 2);
  u16* W2_t = (u16*)carve((size_t)NLAY * 512 * 512 * 2);
  u16* xb = (u16*)carve((size_t)MTOT * NHID * 2);       // 32 MB: layer state
  u16* qk = (u16*)carve((size_t)MTOT * 1024 * 2);       // 64 MB: Q,K / ybuf / Wt_fc
  u16* vbuf = (u16*)carve((size_t)MTOT * NHID * 2);     // 32 MB: V packed
  u16* obuf = (u16*)carve((size_t)MTOT * NHID * 2);     // 32 MB: attn out / hbuf / part
  u32* maskb = (u32*)carve((size_t)NB * MAXN * 4);
  u16* ybuf = qk;                 // pre-LN y (qk dead after attn)
  u16* hbuf = obuf;               // MLP hidden
  u16* Wt_fc = qk;                // FC-time alias: 4 MB
  float* part_fc = (float*)obuf;  // FC-time alias: 16.8 MB

  // --- prep ---
  mask_k<<<NB / 8, 256, 0, stream>>>(adj_bits, maskb);
  embed_k<<<(MTOT * 128) / 256, 256, 0, stream>>>(node_types, Wpos, bpos, Wnode, bnode, xb);
  dim3 tg(16, 16, NLAY);
  tconv_k<<<tg, 256, 0, stream>>>(eWq, Wqkv_t, 0, 1536);
  tconv_k<<<tg, 256, 0, stream>>>(eWk, Wqkv_t, 512, 1536);
  tconv_k<<<tg, 256, 0, stream>>>(eWv, Wqkv_t, 1024, 1536);
  tconv_k<<<tg, 256, 0, stream>>>(eWo, Wo_t, 0, 512);
  tconv_k<<<tg, 256, 0, stream>>>(eW1, W1_t, 0, 512);
  tconv_k<<<tg, 256, 0, stream>>>(eW2, W2_t, 0, 512);

  // --- encoder layers ---
  for (int l = 0; l < NLAY; ++l) {
    size_t lw = (size_t)l * 512 * 512;
    gemm_qkv<<<dim3(12, MTOT / 128), 256, 0, stream>>>(
        xb, Wqkv_t + (size_t)l * 1536 * 512,
        ebq + l * 512, ebk + l * 512, ebv + l * 512, qk, vbuf);
    attn_k<<<NB * NHEAD / 4, 256, 0, stream>>>(qk, vbuf, maskb, obuf);
    gemm_bt<3><<<dim3(4, MTOT / 128), 256, 0, stream>>>(
        obuf, Wo_t + lw, ebo + l * 512, xb, ybuf, 512, 512);
    ln_k<<<MTOT / 4, 256, 0, stream>>>(ybuf, ln1g + l * 512, ln1b + l * 512, xb);
    gemm_bt<2><<<dim3(4, MTOT / 128), 256, 0, stream>>>(
        xb, W1_t + lw, eb1 + l * 512, nullptr, hbuf, 512, 512);
    gemm_bt<3><<<dim3(4, MTOT / 128), 256, 0, stream>>>(
        hbuf, W2_t + lw, eb2 + l * 512, xb, ybuf, 512, 512);
    ln_k<<<MTOT / 4, 256, 0, stream>>>(ybuf, ln2g + l * 512, ln2b + l * 512, xb);
  }

  // --- final FC: transpose weights (dead qk region), K-split MFMA, reduce ---
  fcT_k<<<dim3(256, 2), 256, 0, stream>>>(Wfc1, Wfc2, Wt_fc);
  gemm_fc<<<dim3(32, 8), 256, 0, stream>>>(xb, Wt_fc, part_fc);
  fc_red_k<<<512, 256, 0, stream>>>(part_fc, bfc1, bfc2, (float*)d_out);
}